// Round 7
// baseline (2125.570 us; speedup 1.0000x reference)
//
#include <hip/hip_runtime.h>

#define B_ 64
#define L_ 2048
#define D_ 128
#define LP 2056   // padded rows per batch (3 left, 5 right incl. alignment)
#define PAD 3     // SAME-pad left for W=8

typedef __attribute__((ext_vector_type(8))) short short8;
typedef __attribute__((ext_vector_type(4))) float f32x4;
typedef __attribute__((ext_vector_type(4))) unsigned short us4;

static __device__ __forceinline__ float bf2f(unsigned short u) {
  return __uint_as_float(((unsigned int)u) << 16);
}
static __device__ __forceinline__ unsigned short f2bf(float f) {
  unsigned int x = __float_as_uint(f);
  unsigned int r = (x + 0x7fffu + ((x >> 16) & 1u)) >> 16;  // RNE
  return (unsigned short)r;
}

// ---------------------------------------------------------------------------
// K0: gather tok -> bf16 padded [B,LP,128]; gather bias; transpose weights.
// ---------------------------------------------------------------------------
__global__ __launch_bounds__(256) void k_prep(
    const int* __restrict__ code, const float* __restrict__ E,
    const float* __restrict__ bias_table, const float* __restrict__ Wx,
    const float* __restrict__ c1w, const float* __restrict__ c2w,
    unsigned short* __restrict__ tokpad,
    unsigned short* __restrict__ WxT, unsigned short* __restrict__ c1wT,
    unsigned short* __restrict__ c2wT, float* __restrict__ biasg)
{
  int id = blockIdx.x * 256 + threadIdx.x;
  const int N0 = B_ * LP * 16;            // tokpad in uint4 (8 bf16) chunks
  if (id < N0) {
    int b = id / (LP * 16); int rem = id % (LP * 16);
    int row = rem >> 4, c8 = rem & 15;
    uint4 o = {0u,0u,0u,0u};
    if (row >= PAD && row < PAD + L_) {
      int cd = code[b * L_ + (row - PAD)];
      const float4* e = (const float4*)(E + (size_t)cd * D_ + c8 * 8);
      float4 e0 = e[0], e1 = e[1];
      o.x = f2bf(e0.x) | ((unsigned int)f2bf(e0.y) << 16);
      o.y = f2bf(e0.z) | ((unsigned int)f2bf(e0.w) << 16);
      o.z = f2bf(e1.x) | ((unsigned int)f2bf(e1.y) << 16);
      o.w = f2bf(e1.z) | ((unsigned int)f2bf(e1.w) << 16);
    }
    ((uint4*)tokpad)[id] = o;
    return;
  }
  id -= N0;
  const int N2 = B_ * L_;
  if (id < N2) { biasg[id] = bias_table[code[id]]; return; }
  id -= N2;
  const int N3 = 192 * 128;               // WxT[c][d]
  if (id < N3) { int c = id >> 7, d = id & 127; WxT[id] = f2bf(Wx[d * 192 + c]); return; }
  id -= N3;
  const int N4 = 8 * 64 * 128;            // c1wT[w][c][d]
  if (id < N4) {
    int w = id >> 13, c = (id >> 7) & 63, d = id & 127;
    c1wT[id] = f2bf(c1w[(w * 128 + d) * 64 + c]); return;
  }
  id -= N4;
  const int N5 = 8 * 64 * 64;             // c2wT[w][c][d]
  if (id < N5) {
    int w = id >> 12, c = (id >> 6) & 63, d = id & 63;
    c2wT[id] = f2bf(c2w[(w * 64 + d) * 64 + c]);
  }
}

// ---------------------------------------------------------------------------
// K1: x_proj = tok @ Wx + b_gru[0] -> bf16, GATE-INTERLEAVED per lane:
// xg[b][j][t][{z,r,h,0}] (8 B per step). Same C bits as the R10 kernel
// (same acc, same f2bf); only placement changed so a GRU lane reads ONE
// stream (uint4 = 2 steps).
// ---------------------------------------------------------------------------
__global__ __launch_bounds__(256) void k_xproj(
    const unsigned short* __restrict__ tokpad, const unsigned short* __restrict__ WxT,
    const float* __restrict__ bg, unsigned short* __restrict__ xg)
{
  __shared__ __align__(16) unsigned short At[128 * 136];
  __shared__ __align__(16) unsigned short Bt[192 * 136];
  int b = blockIdx.x >> 4;
  int l0 = (blockIdx.x & 15) << 7;
  int tid = threadIdx.x;
  for (int i = tid; i < 128 * 16; i += 256) {
    int row = i >> 4, c8 = i & 15;
    uint4 v = ((const uint4*)tokpad)[(b * LP + PAD + l0 + row) * 16 + c8];
    *((uint4*)&At[row * 136 + c8 * 8]) = v;
  }
  for (int i = tid; i < 192 * 16; i += 256) {
    int row = i >> 4, c8 = i & 15;
    uint4 v = ((const uint4*)WxT)[i];
    *((uint4*)&Bt[row * 136 + c8 * 8]) = v;
  }
  __syncthreads();
  int wave = tid >> 6, lane = tid & 63;
  int m = lane & 15, q = lane >> 4;
  f32x4 acc[2][12];
  #pragma unroll
  for (int mt = 0; mt < 2; ++mt)
    #pragma unroll
    for (int nt = 0; nt < 12; ++nt) acc[mt][nt] = (f32x4){0.f,0.f,0.f,0.f};
  #pragma unroll
  for (int ks = 0; ks < 4; ++ks) {
    int kof = ks * 32 + q * 8;
    short8 a[2], bb[12];
    #pragma unroll
    for (int mt = 0; mt < 2; ++mt)
      a[mt] = *(const short8*)&At[(wave * 32 + mt * 16 + m) * 136 + kof];
    #pragma unroll
    for (int nt = 0; nt < 12; ++nt)
      bb[nt] = *(const short8*)&Bt[(nt * 16 + m) * 136 + kof];
    #pragma unroll
    for (int mt = 0; mt < 2; ++mt)
      #pragma unroll
      for (int nt = 0; nt < 12; ++nt)
        acc[mt][nt] = __builtin_amdgcn_mfma_f32_16x16x32_bf16(a[mt], bb[nt], acc[mt][nt], 0, 0, 0);
  }
  __syncthreads();                        // all MFMA reads of Bt done
  // deposit C (+bias, bf16) transposed into Bt[c][l]  (l = 0..127)
  #pragma unroll
  for (int mt = 0; mt < 2; ++mt) {
    int lrow = wave * 32 + mt * 16 + q * 4;
    #pragma unroll
    for (int nt = 0; nt < 12; ++nt) {
      int c = nt * 16 + m;                 // C col = lane&15
      float b0 = bg[c];
      us4 val;
      val.x = f2bf(acc[mt][nt][0] + b0);
      val.y = f2bf(acc[mt][nt][1] + b0);
      val.z = f2bf(acc[mt][nt][2] + b0);
      val.w = f2bf(acc[mt][nt][3] + b0);
      *((us4*)&Bt[c * 136 + lrow]) = val;
    }
  }
  __syncthreads();
  // gate-interleaved write-out: per (j, 4-step group): read z/r/h 4-wide,
  // pack [z|r<<16, h] per step, store 2 x uint4 (32 B contiguous per lane).
  for (int i = tid; i < 64 * 32; i += 256) {
    int j = i >> 5, g = i & 31;           // steps l = 4g..4g+3
    us4 z4 = *(const us4*)&Bt[j * 136 + g * 4];
    us4 r4 = *(const us4*)&Bt[(64 + j) * 136 + g * 4];
    us4 h4 = *(const us4*)&Bt[(128 + j) * 136 + g * 4];
    uint4 o0, o1;
    o0.x = (unsigned)z4.x | ((unsigned)r4.x << 16); o0.y = (unsigned)h4.x;
    o0.z = (unsigned)z4.y | ((unsigned)r4.y << 16); o0.w = (unsigned)h4.y;
    o1.x = (unsigned)z4.z | ((unsigned)r4.z << 16); o1.y = (unsigned)h4.z;
    o1.z = (unsigned)z4.w | ((unsigned)r4.w << 16); o1.w = (unsigned)h4.w;
    size_t stp = (size_t)(b * 64 + j) * L_ + l0 + g * 4;  // step index
    ((uint4*)xg)[stp >> 1]       = o0;
    ((uint4*)xg)[(stp >> 1) + 1] = o1;
  }
}

// ---------------------------------------------------------------------------
// K2 (fused): blocks 0..31 = GRU scan (TWO batches per block, interleaved);
// blocks 32..255 = conv1+conv2 with halo recompute. No cross-block deps.
//
// R17 GRU: R16's 3-wave k-split + readlane matvec, now advancing TWO
// independent GRU chains (batches 2*bid, 2*bid+1) per block. Rationale:
// R16's T_step ~1059 cyc = ~450 issue + ~600 pure latency (exchange
// write-wait + barrier + ds_read returns + 4-deep transcendental chain) —
// that latency is irreducible for ONE chain since every op depends on the
// last, but a second independent chain's issue work fills the bubbles.
// Weights are SHARED (Wh is batch-independent): zero extra weight VGPRs.
// Per superstep: readlanes A+B -> fma A+B -> write both partials -> ONE
// shared barrier -> read both -> gates A+B. Per-chain math is bit-identical
// to R16 (same fma order, same (q0+q1)+q2 wave-order sum, same formulas).
// ---------------------------------------------------------------------------
#define BARRIER() asm volatile("s_waitcnt lgkmcnt(0)\n\ts_barrier" ::: "memory")

__global__ __launch_bounds__(192)
__attribute__((amdgpu_waves_per_eu(1, 1)))
void k_fused(
    const unsigned short* __restrict__ xg, const float* __restrict__ Wh,
    const float* __restrict__ bg, float* __restrict__ h_t,
    const unsigned short* __restrict__ tokpad,
    const unsigned short* __restrict__ c1wT, const float* __restrict__ c1b,
    const unsigned short* __restrict__ c2wT, const float* __restrict__ c2b,
    unsigned short* __restrict__ c2o)
{
  __shared__ __align__(16) unsigned short pool[39744];
  int bid = blockIdx.x;
  int tid = threadIdx.x;

  if (bid < 32) {
    // ======== GRU scan (R17: 3-wave k-split, 2 chains interleaved) =======
    int w = tid >> 6, j = tid & 63;
    float* xch = (float*)pool;  // 2 parities x 2 chains x 3 waves x 64 x f32x4
    int b0 = bid * 2, b1 = bid * 2 + 1;
    int kb = w * 22;                      // k-rows kb..kb+21 (padded past 63)

    float wz[22], wr[22], wh[22];
    #pragma unroll
    for (int i = 0; i < 22; ++i) {
      int k = kb + i;
      bool ok = k < 64;
      wz[i] = ok ? Wh[k * 192 + j]       : 0.f;
      wr[i] = ok ? Wh[k * 192 + 64 + j]  : 0.f;
      wh[i] = ok ? Wh[k * 192 + 128 + j] : 0.f;
    }
    #pragma unroll
    for (int i = 0; i < 22; ++i)
      asm volatile("" : "+v"(wz[i]), "+v"(wr[i]), "+v"(wh[i]));

    // bias seeds: only wave 0 carries the bias (fixed-order partial sum).
    float seedz = (w == 0) ? bg[192 + j]       : 0.f;
    float seedr = (w == 0) ? bg[192 + 64 + j]  : 0.f;
    float seedh = (w == 0) ? bg[192 + 128 + j] : 0.f;
    float hregA = 0.f, hregB = 0.f;

    const uint4* xpA = (const uint4*)(xg + (size_t)(b0 * 64 + j) * L_ * 4);
    const uint4* xpB = (const uint4*)(xg + (size_t)(b1 * 64 + j) * L_ * 4);
    uint4 curA = xpA[0], nxtA = xpA[1];
    uint4 curB = xpB[0], nxtB = xpB[1];

#define STEP2(WZRA, WHA, WZRB, WHB, P) { \
    float hkA[22], hkB[22]; \
    _Pragma("unroll") \
    for (int i = 0; i < 22; ++i) { \
      hkA[i] = __int_as_float(__builtin_amdgcn_readlane(__float_as_int(hregA), (kb + i) & 63)); \
      hkB[i] = __int_as_float(__builtin_amdgcn_readlane(__float_as_int(hregB), (kb + i) & 63)); \
    } \
    __builtin_amdgcn_sched_barrier(0); \
    float azA[4] = {seedz, 0.f, 0.f, 0.f}; \
    float arA[4] = {seedr, 0.f, 0.f, 0.f}; \
    float ahA[4] = {seedh, 0.f, 0.f, 0.f}; \
    float azB[4] = {seedz, 0.f, 0.f, 0.f}; \
    float arB[4] = {seedr, 0.f, 0.f, 0.f}; \
    float ahB[4] = {seedh, 0.f, 0.f, 0.f}; \
    _Pragma("unroll") \
    for (int i = 0; i < 22; ++i) { \
      azA[i & 3] = fmaf(hkA[i], wz[i], azA[i & 3]); \
      arA[i & 3] = fmaf(hkA[i], wr[i], arA[i & 3]); \
      ahA[i & 3] = fmaf(hkA[i], wh[i], ahA[i & 3]); \
      azB[i & 3] = fmaf(hkB[i], wz[i], azB[i & 3]); \
      arB[i & 3] = fmaf(hkB[i], wr[i], arB[i & 3]); \
      ahB[i & 3] = fmaf(hkB[i], wh[i], ahB[i & 3]); \
    } \
    float4 pvA, pvB; \
    pvA.x = (azA[0] + azA[1]) + (azA[2] + azA[3]); \
    pvA.y = (arA[0] + arA[1]) + (arA[2] + arA[3]); \
    pvA.z = (ahA[0] + ahA[1]) + (ahA[2] + ahA[3]); \
    pvA.w = 0.f; \
    pvB.x = (azB[0] + azB[1]) + (azB[2] + azB[3]); \
    pvB.y = (arB[0] + arB[1]) + (arB[2] + arB[3]); \
    pvB.z = (ahB[0] + ahB[1]) + (ahB[2] + ahB[3]); \
    pvB.w = 0.f; \
    *((float4*)&xch[(P) * 1536 + 0 * 768 + (w * 64 + j) * 4]) = pvA; \
    *((float4*)&xch[(P) * 1536 + 1 * 768 + (w * 64 + j) * 4]) = pvB; \
    BARRIER(); \
    float4 qA0 = *((const float4*)&xch[(P) * 1536 + 0 * 768 + (0 * 64 + j) * 4]); \
    float4 qA1 = *((const float4*)&xch[(P) * 1536 + 0 * 768 + (1 * 64 + j) * 4]); \
    float4 qA2 = *((const float4*)&xch[(P) * 1536 + 0 * 768 + (2 * 64 + j) * 4]); \
    float4 qB0 = *((const float4*)&xch[(P) * 1536 + 1 * 768 + (0 * 64 + j) * 4]); \
    float4 qB1 = *((const float4*)&xch[(P) * 1536 + 1 * 768 + (1 * 64 + j) * 4]); \
    float4 qB2 = *((const float4*)&xch[(P) * 1536 + 1 * 768 + (2 * 64 + j) * 4]); \
    float szA = (qA0.x + qA1.x) + qA2.x; \
    float srA = (qA0.y + qA1.y) + qA2.y; \
    float shA = (qA0.z + qA1.z) + qA2.z; \
    float szB = (qB0.x + qB1.x) + qB2.x; \
    float srB = (qB0.y + qB1.y) + qB2.y; \
    float shB = (qB0.z + qB1.z) + qB2.z; \
    float xvzA = bf2f((unsigned short)((WZRA) & 0xffffu)); \
    float xvrA = bf2f((unsigned short)((WZRA) >> 16)); \
    float xvhA = bf2f((unsigned short)((WHA) & 0xffffu)); \
    float xvzB = bf2f((unsigned short)((WZRB) & 0xffffu)); \
    float xvrB = bf2f((unsigned short)((WZRB) >> 16)); \
    float xvhB = bf2f((unsigned short)((WHB) & 0xffffu)); \
    float zgA = 1.f / (1.f + __expf(-(xvzA + szA))); \
    float rgA = 1.f / (1.f + __expf(-(xvrA + srA))); \
    float zgB = 1.f / (1.f + __expf(-(xvzB + szB))); \
    float rgB = 1.f / (1.f + __expf(-(xvrB + srB))); \
    float e2A = __expf(-2.f * (xvhA + rgA * shA)); \
    float e2B = __expf(-2.f * (xvhB + rgB * shB)); \
    float hhA = fmaf(2.f, __frcp_rn(1.f + e2A), -1.f); \
    float hhB = fmaf(2.f, __frcp_rn(1.f + e2B), -1.f); \
    hregA = zgA * hregA + (1.f - zgA) * hhA; \
    hregB = zgB * hregB + (1.f - zgB) * hhB; \
  }

    #pragma nounroll
    for (int p = 0; p < L_ / 2; ++p) {
      int pn = (p < L_ / 2 - 2) ? p + 2 : (L_ / 2 - 1);
      uint4 nnA = xpA[pn];
      uint4 nnB = xpB[pn];
      STEP2(curA.x, curA.y, curB.x, curB.y, 0)
      STEP2(curA.z, curA.w, curB.z, curB.w, 1)
      curA = nxtA; nxtA = nnA;
      curB = nxtB; nxtB = nnB;
    }
#undef STEP2
    if (w == 0) {
      h_t[b0 * 64 + j] = hregA;
      h_t[b1 * 64 + j] = hregB;
    }
    return;
  }

  // ================= fused conv1+conv2 (halo recompute) =================
  unsigned short* At    = pool;           // 152 x 136 shorts = 41344 B
  unsigned short* l1buf = pool + 20672;   // 144 x 72  shorts = 20736 B
  unsigned short* Bw    = pool + 31040;   //  64 x 136 shorts = 17408 B
  int wv = tid >> 6, lane = tid & 63;
  int m = lane & 15, q = lane >> 4;

  for (int job = bid - 32; job < 1024; job += 224) {
    int b = job >> 4;
    int l0 = (job & 15) << 7;
    __syncthreads();                      // prev job fully consumed
    for (int i = tid; i < 152 * 16; i += 192) {
      int row = i >> 4, c8 = i & 15;
      int p = l0 - 3 + row;
      p = p < 0 ? 0 : (p > 2055 ? 2055 : p);
      *((uint4*)&At[row * 136 + c8 * 8]) = ((const uint4*)tokpad)[(b * LP + p) * 16 + c8];
    }
    // ---- conv1: l1 rows [l0-3, l0+140] (9 M-tiles of 16), K=128 ----
    f32x4 acc[3][4];
    #pragma unroll
    for (int mt = 0; mt < 3; ++mt)
      #pragma unroll
      for (int nt = 0; nt < 4; ++nt) acc[mt][nt] = (f32x4){0.f,0.f,0.f,0.f};
    for (int w8 = 0; w8 < 8; ++w8) {
      __syncthreads();
      for (int i = tid; i < 64 * 16; i += 192) {
        int row = i >> 4, c8 = i & 15;
        *((uint4*)&Bw[row * 136 + c8 * 8]) = ((const uint4*)c1wT)[(w8 * 64 + row) * 16 + c8];
      }
      __syncthreads();
      #pragma unroll
      for (int ks = 0; ks < 4; ++ks) {
        int kof = ks * 32 + q * 8;
        short8 a[3], bb[4];
        #pragma unroll
        for (int mt = 0; mt < 3; ++mt) {
          int tl = wv + 3 * mt;
          a[mt] = *(const short8*)&At[(tl * 16 + m + w8) * 136 + kof];
        }
        #pragma unroll
        for (int nt = 0; nt < 4; ++nt)
          bb[nt] = *(const short8*)&Bw[(nt * 16 + m) * 136 + kof];
        #pragma unroll
        for (int mt = 0; mt < 3; ++mt)
          #pragma unroll
          for (int nt = 0; nt < 4; ++nt)
            acc[mt][nt] = __builtin_amdgcn_mfma_f32_16x16x32_bf16(a[mt], bb[nt], acc[mt][nt], 0, 0, 0);
      }
    }
    #pragma unroll
    for (int mt = 0; mt < 3; ++mt) {
      int tl = wv + 3 * mt;
      #pragma unroll
      for (int nt = 0; nt < 4; ++nt) {
        int c = nt * 16 + m;
        float bs = c1b[c];
        #pragma unroll
        for (int r = 0; r < 4; ++r) {
          float v = fmaxf(acc[mt][nt][r] + bs, 0.f);
          l1buf[(tl * 16 + q * 4 + r) * 72 + c] = f2bf(v);
        }
      }
    }
    __syncthreads();
    for (int i2 = tid; i2 < 135 * 8; i2 += 192) {
      int i = i2 >> 3, c8 = i2 & 7;
      int jrow = l0 - 3 + i;
      if (jrow < 0 || jrow > 2047) {
        uint4 z4 = {0u,0u,0u,0u};
        *((uint4*)&l1buf[i * 72 + c8 * 8]) = z4;
      }
    }
    // ---- conv2: out rows [l0, l0+127] (8 M-tiles), K=64 ----
    f32x4 acc2[3][4];
    #pragma unroll
    for (int mt = 0; mt < 3; ++mt)
      #pragma unroll
      for (int nt = 0; nt < 4; ++nt) acc2[mt][nt] = (f32x4){0.f,0.f,0.f,0.f};
    for (int w8 = 0; w8 < 8; ++w8) {
      __syncthreads();
      for (int i = tid; i < 64 * 8; i += 192) {
        int row = i >> 3, c8 = i & 7;
        *((uint4*)&Bw[row * 72 + c8 * 8]) = ((const uint4*)c2wT)[(w8 * 64 + row) * 8 + c8];
      }
      __syncthreads();
      #pragma unroll
      for (int ks = 0; ks < 2; ++ks) {
        int kof = ks * 32 + q * 8;
        short8 a[3], bb[4];
        #pragma unroll
        for (int mt = 0; mt < 3; ++mt) {
          int tl = wv + 3 * mt;
          if (tl < 8)
            a[mt] = *(const short8*)&l1buf[(tl * 16 + m + w8) * 72 + kof];
        }
        #pragma unroll
        for (int nt = 0; nt < 4; ++nt)
          bb[nt] = *(const short8*)&Bw[(nt * 16 + m) * 72 + kof];
        #pragma unroll
        for (int mt = 0; mt < 3; ++mt) {
          int tl = wv + 3 * mt;
          if (tl < 8)
            #pragma unroll
            for (int nt = 0; nt < 4; ++nt)
              acc2[mt][nt] = __builtin_amdgcn_mfma_f32_16x16x32_bf16(a[mt], bb[nt], acc2[mt][nt], 0, 0, 0);
        }
      }
    }
    #pragma unroll
    for (int mt = 0; mt < 3; ++mt) {
      int tl = wv + 3 * mt;
      if (tl < 8) {
        #pragma unroll
        for (int nt = 0; nt < 4; ++nt) {
          int c = nt * 16 + m;
          float bs = c2b[c];
          #pragma unroll
          for (int r = 0; r < 4; ++r)
            c2o[(size_t)(b * L_ + l0 + tl * 16 + q * 4 + r) * 64 + c] = f2bf(acc2[mt][nt][r] + bs);
        }
      }
    }
  }
}

// ---------------------------------------------------------------------------
// K5: per-batch tail: L2=c2o*h_t -> l2norm -> conv3 -> softmax alpha ->
//     n_hat = sum alpha*tok -> logits = tok.n_hat + bias -> softmax -> out
// ---------------------------------------------------------------------------
__global__ __launch_bounds__(256) void k_final(
    const unsigned short* __restrict__ tokpad, const unsigned short* __restrict__ c2o,
    const float* __restrict__ h_t, const float* __restrict__ c3w,
    const float* __restrict__ c3b, const float* __restrict__ biasg,
    float* __restrict__ out)
{
  __shared__ float Lf[71 * 65];
  __shared__ float a_lds[2048];
  __shared__ float l_lds[2048];
  __shared__ float red[256];
  __shared__ float nred[512];
  __shared__ float nhat[128];
  __shared__ float ht[64];
  __shared__ float c3[512];
  int b = blockIdx.x, tid = threadIdx.x, lane = tid & 63, wave = tid >> 6;
  if (tid < 64) ht[tid] = h_t[b * 64 + tid];
  for (int i = tid; i < 512; i += 256) c3[i] = c3w[i];
  float c3bias = c3b[0];
  __syncthreads();
  // ---- pass 1: a_logits via normalized features + conv3 (tiles of 64 l) ----
  for (int tile = 0; tile < 32; ++tile) {
    int lt = tile << 6;
    for (int i0 = wave; i0 < 71; i0 += 4) {
      int l = lt - 3 + i0;
      float v = 0.f;
      if (l >= 0 && l < L_) v = bf2f(c2o[((size_t)b * L_ + l) * 64 + lane]) * ht[lane];
      float ss = v * v;
      #pragma unroll
      for (int msk = 1; msk < 64; msk <<= 1) ss += __shfl_xor(ss, msk);
      Lf[i0 * 65 + lane] = v * rsqrtf(ss + 1e-12f);
    }
    __syncthreads();
    {
      int u = lane, part = wave;
      float p = 0.f;
      #pragma unroll
      for (int w = 0; w < 8; ++w)
        #pragma unroll
        for (int cc = 0; cc < 16; ++cc) {
          int c = part * 16 + cc;
          p += Lf[(u + w) * 65 + c] * c3[w * 64 + c];
        }
      red[tid] = p;
    }
    __syncthreads();
    if (tid < 64) a_lds[lt + tid] = red[tid] + red[64 + tid] + red[128 + tid] + red[192 + tid] + c3bias;
    __syncthreads();
  }
  // ---- pass 2: softmax alpha over 2048 ----
  {
    float mx = -1e30f;
    for (int i = tid; i < 2048; i += 256) mx = fmaxf(mx, a_lds[i]);
    #pragma unroll
    for (int msk = 1; msk < 64; msk <<= 1) mx = fmaxf(mx, __shfl_xor(mx, msk));
    if (lane == 0) red[wave] = mx;
    __syncthreads();
    mx = fmaxf(fmaxf(red[0], red[1]), fmaxf(red[2], red[3]));
    float sm = 0.f;
    for (int i = tid; i < 2048; i += 256) sm += __expf(a_lds[i] - mx);
    #pragma unroll
    for (int msk = 1; msk < 64; msk <<= 1) sm += __shfl_xor(sm, msk);
    __syncthreads();
    if (lane == 0) red[wave] = sm;
    __syncthreads();
    sm = red[0] + red[1] + red[2] + red[3];
    float inv = 1.f / sm;
    for (int i = tid; i < 2048; i += 256) a_lds[i] = __expf(a_lds[i] - mx) * inv;
    __syncthreads();
  }
  // ---- pass 3: n_hat[128] = sum_l alpha_l * tok[l][:] ----
  {
    int d2 = tid & 63, g = tid >> 6;
    float ax = 0.f, ay = 0.f;
    for (int l = g; l < L_; l += 4) {
      unsigned int uu = *(const unsigned int*)&tokpad[((size_t)b * LP + PAD + l) * 128 + d2 * 2];
      float al = a_lds[l];
      ax += al * bf2f((unsigned short)(uu & 0xffffu));
      ay += al * bf2f((unsigned short)(uu >> 16));
    }
    nred[g * 128 + d2 * 2] = ax;
    nred[g * 128 + d2 * 2 + 1] = ay;
    __syncthreads();
    if (tid < 128) nhat[tid] = nred[tid] + nred[128 + tid] + nred[256 + tid] + nred[384 + tid];
    __syncthreads();
  }
  // ---- pass 4: logits = tok . n_hat + bias ----
  for (int li = 0; li < 8; ++li) {
    int l = li * 256 + tid;
    const uint4* rowp = (const uint4*)&tokpad[((size_t)b * LP + PAD + l) * 128];
    float s = 0.f;
    #pragma unroll
    for (int jj = 0; jj < 16; ++jj) {
      uint4 uu = rowp[jj];
      s += bf2f((unsigned short)(uu.x & 0xffffu)) * nhat[jj*8+0]
         + bf2f((unsigned short)(uu.x >> 16))     * nhat[jj*8+1]
         + bf2f((unsigned short)(uu.y & 0xffffu)) * nhat[jj*8+2]
         + bf2f((unsigned short)(uu.y >> 16))     * nhat[jj*8+3]
         + bf2f((unsigned short)(uu.z & 0xffffu)) * nhat[jj*8+4]
         + bf2f((unsigned short)(uu.z >> 16))     * nhat[jj*8+5]
         + bf2f((unsigned short)(uu.w & 0xffffu)) * nhat[jj*8+6]
         + bf2f((unsigned short)(uu.w >> 16))     * nhat[jj*8+7];
    }
    l_lds[l] = s + biasg[b * L_ + l];
  }
  __syncthreads();
  // ---- pass 5: final softmax -> out ----
  {
    float mx = -1e30f;
    for (int i = tid; i < 2048; i += 256) mx = fmaxf(mx, l_lds[i]);
    #pragma unroll
    for (int msk = 1; msk < 64; msk <<= 1) mx = fmaxf(mx, __shfl_xor(mx, msk));
    __syncthreads();
    if (lane == 0) red[wave] = mx;
    __syncthreads();
    mx = fmaxf(fmaxf(red[0], red[1]), fmaxf(red[2], red[3]));
    float sm = 0.f;
    for (int i = tid; i < 2048; i += 256) sm += __expf(l_lds[i] - mx);
    #pragma unroll
    for (int msk = 1; msk < 64; msk <<= 1) sm += __shfl_xor(sm, msk);
    __syncthreads();
    if (lane == 0) red[wave] = sm;
    __syncthreads();
    sm = red[0] + red[1] + red[2] + red[3];
    float inv = 1.f / sm;
    for (int i = tid; i < 2048; i += 256) out[b * L_ + i] = __expf(l_lds[i] - mx) * inv;
  }
}

// ---------------------------------------------------------------------------
extern "C" void kernel_launch(void* const* d_in, const int* in_sizes, int n_in,
                              void* d_out, int out_size, void* d_ws, size_t ws_size,
                              hipStream_t stream) {
  const int*   code = (const int*)d_in[0];
  const float* E    = (const float*)d_in[1];
  const float* bt   = (const float*)d_in[2];
  const float* Wx   = (const float*)d_in[3];
  const float* Wh   = (const float*)d_in[4];
  const float* bg   = (const float*)d_in[5];
  const float* c1w  = (const float*)d_in[6];
  const float* c1b  = (const float*)d_in[7];
  const float* c2w  = (const float*)d_in[8];
  const float* c2b  = (const float*)d_in[9];
  const float* c3w  = (const float*)d_in[10];
  const float* c3b  = (const float*)d_in[11];
  char* ws = (char*)d_ws;
  unsigned short* tokpad = (unsigned short*)(ws);               // 33,685,504 B
  unsigned short* xg     = (unsigned short*)(ws + 33685504);    // 67,108,864 B
  unsigned short* c2o    = (unsigned short*)(ws + 100794368);   // 16,777,216 B
  unsigned short* WxT    = (unsigned short*)(ws + 117571584);   //     49,152 B
  unsigned short* c1wT   = (unsigned short*)(ws + 117620736);   //    131,072 B
  unsigned short* c2wT   = (unsigned short*)(ws + 117751808);   //     65,536 B
  float*          htp    = (float*)(ws + 117817344);            //     16,384 B
  float*          biasg  = (float*)(ws + 117833728);            //    524,288 B
  // total ws use: 118,358,016 B

  k_prep <<<9216, 256, 0, stream>>>(code, E, bt, Wx, c1w, c2w, tokpad, WxT, c1wT, c2wT, biasg);
  k_xproj<<<1024, 256, 0, stream>>>(tokpad, WxT, bg, xg);
  k_fused<<<256, 192, 0, stream>>>(xg, Wh, bg, htp, tokpad, c1wT, c1b, c2wT, c2b, c2o);
  k_final<<<64, 256, 0, stream>>>(tokpad, c2o, htp, c3w, c3b, biasg, (float*)d_out);
}

// Round 8
// 1513.903 us; speedup vs baseline: 1.4040x; 1.4040x over previous
//
#include <hip/hip_runtime.h>

#define B_ 64
#define L_ 2048
#define D_ 128
#define LP 2056   // padded rows per batch (3 left, 5 right incl. alignment)
#define PAD 3     // SAME-pad left for W=8

typedef __attribute__((ext_vector_type(8))) short short8;
typedef __attribute__((ext_vector_type(4))) float f32x4;
typedef __attribute__((ext_vector_type(4))) unsigned short us4;

static __device__ __forceinline__ float bf2f(unsigned short u) {
  return __uint_as_float(((unsigned int)u) << 16);
}
static __device__ __forceinline__ unsigned short f2bf(float f) {
  unsigned int x = __float_as_uint(f);
  unsigned int r = (x + 0x7fffu + ((x >> 16) & 1u)) >> 16;  // RNE
  return (unsigned short)r;
}

// ---------------------------------------------------------------------------
// K0: gather tok -> bf16 padded [B,LP,128]; gather bias; transpose weights.
// ---------------------------------------------------------------------------
__global__ __launch_bounds__(256) void k_prep(
    const int* __restrict__ code, const float* __restrict__ E,
    const float* __restrict__ bias_table, const float* __restrict__ Wx,
    const float* __restrict__ c1w, const float* __restrict__ c2w,
    unsigned short* __restrict__ tokpad,
    unsigned short* __restrict__ WxT, unsigned short* __restrict__ c1wT,
    unsigned short* __restrict__ c2wT, float* __restrict__ biasg)
{
  int id = blockIdx.x * 256 + threadIdx.x;
  const int N0 = B_ * LP * 16;            // tokpad in uint4 (8 bf16) chunks
  if (id < N0) {
    int b = id / (LP * 16); int rem = id % (LP * 16);
    int row = rem >> 4, c8 = rem & 15;
    uint4 o = {0u,0u,0u,0u};
    if (row >= PAD && row < PAD + L_) {
      int cd = code[b * L_ + (row - PAD)];
      const float4* e = (const float4*)(E + (size_t)cd * D_ + c8 * 8);
      float4 e0 = e[0], e1 = e[1];
      o.x = f2bf(e0.x) | ((unsigned int)f2bf(e0.y) << 16);
      o.y = f2bf(e0.z) | ((unsigned int)f2bf(e0.w) << 16);
      o.z = f2bf(e1.x) | ((unsigned int)f2bf(e1.y) << 16);
      o.w = f2bf(e1.z) | ((unsigned int)f2bf(e1.w) << 16);
    }
    ((uint4*)tokpad)[id] = o;
    return;
  }
  id -= N0;
  const int N2 = B_ * L_;
  if (id < N2) { biasg[id] = bias_table[code[id]]; return; }
  id -= N2;
  const int N3 = 192 * 128;               // WxT[c][d]
  if (id < N3) { int c = id >> 7, d = id & 127; WxT[id] = f2bf(Wx[d * 192 + c]); return; }
  id -= N3;
  const int N4 = 8 * 64 * 128;            // c1wT[w][c][d]
  if (id < N4) {
    int w = id >> 13, c = (id >> 7) & 63, d = id & 127;
    c1wT[id] = f2bf(c1w[(w * 128 + d) * 64 + c]); return;
  }
  id -= N4;
  const int N5 = 8 * 64 * 64;             // c2wT[w][c][d]
  if (id < N5) {
    int w = id >> 12, c = (id >> 6) & 63, d = id & 63;
    c2wT[id] = f2bf(c2w[(w * 64 + d) * 64 + c]);
  }
}

// ---------------------------------------------------------------------------
// K1: x_proj = tok @ Wx + b_gru[0] -> bf16, GATE-INTERLEAVED per lane:
// xg[b][j][t][{z,r,h,0}] (8 B per step). Same C bits as the R10 kernel
// (same acc, same f2bf); only placement changed so a GRU lane reads ONE
// stream (uint4 = 2 steps).
// ---------------------------------------------------------------------------
__global__ __launch_bounds__(256) void k_xproj(
    const unsigned short* __restrict__ tokpad, const unsigned short* __restrict__ WxT,
    const float* __restrict__ bg, unsigned short* __restrict__ xg)
{
  __shared__ __align__(16) unsigned short At[128 * 136];
  __shared__ __align__(16) unsigned short Bt[192 * 136];
  int b = blockIdx.x >> 4;
  int l0 = (blockIdx.x & 15) << 7;
  int tid = threadIdx.x;
  for (int i = tid; i < 128 * 16; i += 256) {
    int row = i >> 4, c8 = i & 15;
    uint4 v = ((const uint4*)tokpad)[(b * LP + PAD + l0 + row) * 16 + c8];
    *((uint4*)&At[row * 136 + c8 * 8]) = v;
  }
  for (int i = tid; i < 192 * 16; i += 256) {
    int row = i >> 4, c8 = i & 15;
    uint4 v = ((const uint4*)WxT)[i];
    *((uint4*)&Bt[row * 136 + c8 * 8]) = v;
  }
  __syncthreads();
  int wave = tid >> 6, lane = tid & 63;
  int m = lane & 15, q = lane >> 4;
  f32x4 acc[2][12];
  #pragma unroll
  for (int mt = 0; mt < 2; ++mt)
    #pragma unroll
    for (int nt = 0; nt < 12; ++nt) acc[mt][nt] = (f32x4){0.f,0.f,0.f,0.f};
  #pragma unroll
  for (int ks = 0; ks < 4; ++ks) {
    int kof = ks * 32 + q * 8;
    short8 a[2], bb[12];
    #pragma unroll
    for (int mt = 0; mt < 2; ++mt)
      a[mt] = *(const short8*)&At[(wave * 32 + mt * 16 + m) * 136 + kof];
    #pragma unroll
    for (int nt = 0; nt < 12; ++nt)
      bb[nt] = *(const short8*)&Bt[(nt * 16 + m) * 136 + kof];
    #pragma unroll
    for (int mt = 0; mt < 2; ++mt)
      #pragma unroll
      for (int nt = 0; nt < 12; ++nt)
        acc[mt][nt] = __builtin_amdgcn_mfma_f32_16x16x32_bf16(a[mt], bb[nt], acc[mt][nt], 0, 0, 0);
  }
  __syncthreads();                        // all MFMA reads of Bt done
  // deposit C (+bias, bf16) transposed into Bt[c][l]  (l = 0..127)
  #pragma unroll
  for (int mt = 0; mt < 2; ++mt) {
    int lrow = wave * 32 + mt * 16 + q * 4;
    #pragma unroll
    for (int nt = 0; nt < 12; ++nt) {
      int c = nt * 16 + m;                 // C col = lane&15
      float b0 = bg[c];
      us4 val;
      val.x = f2bf(acc[mt][nt][0] + b0);
      val.y = f2bf(acc[mt][nt][1] + b0);
      val.z = f2bf(acc[mt][nt][2] + b0);
      val.w = f2bf(acc[mt][nt][3] + b0);
      *((us4*)&Bt[c * 136 + lrow]) = val;
    }
  }
  __syncthreads();
  // gate-interleaved write-out: per (j, 4-step group): read z/r/h 4-wide,
  // pack [z|r<<16, h] per step, store 2 x uint4 (32 B contiguous per lane).
  for (int i = tid; i < 64 * 32; i += 256) {
    int j = i >> 5, g = i & 31;           // steps l = 4g..4g+3
    us4 z4 = *(const us4*)&Bt[j * 136 + g * 4];
    us4 r4 = *(const us4*)&Bt[(64 + j) * 136 + g * 4];
    us4 h4 = *(const us4*)&Bt[(128 + j) * 136 + g * 4];
    uint4 o0, o1;
    o0.x = (unsigned)z4.x | ((unsigned)r4.x << 16); o0.y = (unsigned)h4.x;
    o0.z = (unsigned)z4.y | ((unsigned)r4.y << 16); o0.w = (unsigned)h4.y;
    o1.x = (unsigned)z4.z | ((unsigned)r4.z << 16); o1.y = (unsigned)h4.z;
    o1.z = (unsigned)z4.w | ((unsigned)r4.w << 16); o1.w = (unsigned)h4.w;
    size_t stp = (size_t)(b * 64 + j) * L_ + l0 + g * 4;  // step index
    ((uint4*)xg)[stp >> 1]       = o0;
    ((uint4*)xg)[(stp >> 1) + 1] = o1;
  }
}

// ---------------------------------------------------------------------------
// K2 (fused, 256 threads): blocks 0..63 = GRU scan (4-wave k-split);
// blocks 64..255 = conv1+conv2 with halo recompute (re-mapped to 4 waves).
//
// R18 GRU: R17's 2-chain interleave REVERTED (wall clock = 2048 x T_super;
// adding chain B's work to the superstep lengthened it 1059->1799 — chains
// were already parallel across blocks; per-chain throughput is irrelevant).
// This round shrinks the single-chain T_step's ISSUE portion: 4-wave
// k-split (k=16/wave, 4x16=64 exactly — no padding): readlanes 22->16,
// fma 66->48 per wave. Exchange: 4 float4 partials (one extra ds_read
// issue, same ~120cyc latency). Fixed-order sum (q0+q1)+(q2+q3) -> bitwise
// identical across waves. f32 k-association changes vs R16 (4-way); R15/R16
// showed reassociation leaves absmax at the bf16-quantization floor.
// Conv re-map for 4 waves: conv1 9 M-tiles tl=wv+4*mt (mt<3, mask tl<9);
// conv2 8 tiles tl=wv+4*mt (mt<2, exact). Loader strides 192->256.
// Same LDS layout, same rounding -> conv bits identical.
// ---------------------------------------------------------------------------
#define BARRIER() asm volatile("s_waitcnt lgkmcnt(0)\n\ts_barrier" ::: "memory")

__global__ __launch_bounds__(256)
__attribute__((amdgpu_waves_per_eu(1, 1)))
void k_fused(
    const unsigned short* __restrict__ xg, const float* __restrict__ Wh,
    const float* __restrict__ bg, float* __restrict__ h_t,
    const unsigned short* __restrict__ tokpad,
    const unsigned short* __restrict__ c1wT, const float* __restrict__ c1b,
    const unsigned short* __restrict__ c2wT, const float* __restrict__ c2b,
    unsigned short* __restrict__ c2o)
{
  __shared__ __align__(16) unsigned short pool[39744];
  int bid = blockIdx.x;
  int tid = threadIdx.x;

  if (bid < 64) {
    // ========= GRU scan (R18: 4-wave k-split, readlane h-broadcast) ======
    int w = tid >> 6, j = tid & 63;
    float* xch = (float*)pool;            // 2 parities x 4 waves x 64 x f32x4
    int b = bid;
    int kb = w * 16;                      // k-rows kb..kb+15

    float wz[16], wr[16], wh[16];
    #pragma unroll
    for (int i = 0; i < 16; ++i) {
      int k = kb + i;
      wz[i] = Wh[k * 192 + j];
      wr[i] = Wh[k * 192 + 64 + j];
      wh[i] = Wh[k * 192 + 128 + j];
    }
    #pragma unroll
    for (int i = 0; i < 16; ++i)
      asm volatile("" : "+v"(wz[i]), "+v"(wr[i]), "+v"(wh[i]));

    // bias seeds: only wave 0 carries the bias (fixed-order partial sum).
    float seedz = (w == 0) ? bg[192 + j]       : 0.f;
    float seedr = (w == 0) ? bg[192 + 64 + j]  : 0.f;
    float seedh = (w == 0) ? bg[192 + 128 + j] : 0.f;
    float hreg = 0.f;

    const uint4* xp = (const uint4*)(xg + (size_t)(b * 64 + j) * L_ * 4);
    uint4 cur_ = xp[0];
    uint4 nxt_ = xp[1];

#define STEP(WZR, WH_, P) { \
    float hk[16]; \
    _Pragma("unroll") \
    for (int i = 0; i < 16; ++i) \
      hk[i] = __int_as_float(__builtin_amdgcn_readlane(__float_as_int(hreg), kb + i)); \
    __builtin_amdgcn_sched_barrier(0); \
    float az[4] = {seedz, 0.f, 0.f, 0.f}; \
    float ar[4] = {seedr, 0.f, 0.f, 0.f}; \
    float ah[4] = {seedh, 0.f, 0.f, 0.f}; \
    _Pragma("unroll") \
    for (int i = 0; i < 16; ++i) { \
      az[i & 3] = fmaf(hk[i], wz[i], az[i & 3]); \
      ar[i & 3] = fmaf(hk[i], wr[i], ar[i & 3]); \
      ah[i & 3] = fmaf(hk[i], wh[i], ah[i & 3]); \
    } \
    float4 pv; \
    pv.x = (az[0] + az[1]) + (az[2] + az[3]); \
    pv.y = (ar[0] + ar[1]) + (ar[2] + ar[3]); \
    pv.z = (ah[0] + ah[1]) + (ah[2] + ah[3]); \
    pv.w = 0.f; \
    *((float4*)&xch[(P) * 1024 + (w * 64 + j) * 4]) = pv; \
    BARRIER(); \
    float4 q0 = *((const float4*)&xch[(P) * 1024 + (0 * 64 + j) * 4]); \
    float4 q1 = *((const float4*)&xch[(P) * 1024 + (1 * 64 + j) * 4]); \
    float4 q2 = *((const float4*)&xch[(P) * 1024 + (2 * 64 + j) * 4]); \
    float4 q3 = *((const float4*)&xch[(P) * 1024 + (3 * 64 + j) * 4]); \
    float sz = (q0.x + q1.x) + (q2.x + q3.x); \
    float sr = (q0.y + q1.y) + (q2.y + q3.y); \
    float sh = (q0.z + q1.z) + (q2.z + q3.z); \
    float xvz = bf2f((unsigned short)((WZR) & 0xffffu)); \
    float xvr = bf2f((unsigned short)((WZR) >> 16)); \
    float xvh = bf2f((unsigned short)((WH_) & 0xffffu)); \
    float zg = 1.f / (1.f + __expf(-(xvz + sz))); \
    float rg = 1.f / (1.f + __expf(-(xvr + sr))); \
    float e2 = __expf(-2.f * (xvh + rg * sh)); \
    float hh = fmaf(2.f, __frcp_rn(1.f + e2), -1.f); \
    hreg = zg * hreg + (1.f - zg) * hh; \
  }

    #pragma nounroll
    for (int p = 0; p < L_ / 2; ++p) {
      int pn = (p < L_ / 2 - 2) ? p + 2 : (L_ / 2 - 1);
      uint4 nn = xp[pn];
      STEP(cur_.x, cur_.y, 0)
      STEP(cur_.z, cur_.w, 1)
      cur_ = nxt_; nxt_ = nn;
    }
#undef STEP
    if (w == 0) h_t[b * 64 + j] = hreg;
    return;
  }

  // ============ fused conv1+conv2 (halo recompute, 4 waves) =============
  unsigned short* At    = pool;           // 152 x 136 shorts = 41344 B
  unsigned short* l1buf = pool + 20672;   // 144 x 72  shorts = 20736 B
  unsigned short* Bw    = pool + 31040;   //  64 x 136 shorts = 17408 B
  int wv = tid >> 6, lane = tid & 63;
  int m = lane & 15, q = lane >> 4;

  for (int job = bid - 64; job < 1024; job += 192) {
    int b = job >> 4;
    int l0 = (job & 15) << 7;
    __syncthreads();                      // prev job fully consumed
    for (int i = tid; i < 152 * 16; i += 256) {
      int row = i >> 4, c8 = i & 15;
      int p = l0 - 3 + row;
      p = p < 0 ? 0 : (p > 2055 ? 2055 : p);
      *((uint4*)&At[row * 136 + c8 * 8]) = ((const uint4*)tokpad)[(b * LP + p) * 16 + c8];
    }
    // ---- conv1: l1 rows [l0-3, l0+140] (9 M-tiles of 16), K=128 ----
    // 4 waves: tl = wv + 4*mt, mt<3, mask tl<9 (bijection onto 0..8).
    f32x4 acc[3][4];
    #pragma unroll
    for (int mt = 0; mt < 3; ++mt)
      #pragma unroll
      for (int nt = 0; nt < 4; ++nt) acc[mt][nt] = (f32x4){0.f,0.f,0.f,0.f};
    for (int w8 = 0; w8 < 8; ++w8) {
      __syncthreads();
      for (int i = tid; i < 64 * 16; i += 256) {
        int row = i >> 4, c8 = i & 15;
        *((uint4*)&Bw[row * 136 + c8 * 8]) = ((const uint4*)c1wT)[(w8 * 64 + row) * 16 + c8];
      }
      __syncthreads();
      #pragma unroll
      for (int ks = 0; ks < 4; ++ks) {
        int kof = ks * 32 + q * 8;
        short8 a[3], bb[4];
        #pragma unroll
        for (int mt = 0; mt < 3; ++mt) {
          int tl = wv + 4 * mt;
          if (tl < 9)
            a[mt] = *(const short8*)&At[(tl * 16 + m + w8) * 136 + kof];
        }
        #pragma unroll
        for (int nt = 0; nt < 4; ++nt)
          bb[nt] = *(const short8*)&Bw[(nt * 16 + m) * 136 + kof];
        #pragma unroll
        for (int mt = 0; mt < 3; ++mt) {
          int tl = wv + 4 * mt;
          if (tl < 9)
            #pragma unroll
            for (int nt = 0; nt < 4; ++nt)
              acc[mt][nt] = __builtin_amdgcn_mfma_f32_16x16x32_bf16(a[mt], bb[nt], acc[mt][nt], 0, 0, 0);
        }
      }
    }
    #pragma unroll
    for (int mt = 0; mt < 3; ++mt) {
      int tl = wv + 4 * mt;
      if (tl < 9) {
        #pragma unroll
        for (int nt = 0; nt < 4; ++nt) {
          int c = nt * 16 + m;
          float bs = c1b[c];
          #pragma unroll
          for (int r = 0; r < 4; ++r) {
            float v = fmaxf(acc[mt][nt][r] + bs, 0.f);
            l1buf[(tl * 16 + q * 4 + r) * 72 + c] = f2bf(v);
          }
        }
      }
    }
    __syncthreads();
    for (int i2 = tid; i2 < 135 * 8; i2 += 256) {
      int i = i2 >> 3, c8 = i2 & 7;
      int jrow = l0 - 3 + i;
      if (jrow < 0 || jrow > 2047) {
        uint4 z4 = {0u,0u,0u,0u};
        *((uint4*)&l1buf[i * 72 + c8 * 8]) = z4;
      }
    }
    // ---- conv2: out rows [l0, l0+127] (8 M-tiles), K=64 ----
    // 4 waves: tl = wv + 4*mt, mt<2 (exactly 8 tiles).
    f32x4 acc2[2][4];
    #pragma unroll
    for (int mt = 0; mt < 2; ++mt)
      #pragma unroll
      for (int nt = 0; nt < 4; ++nt) acc2[mt][nt] = (f32x4){0.f,0.f,0.f,0.f};
    for (int w8 = 0; w8 < 8; ++w8) {
      __syncthreads();
      for (int i = tid; i < 64 * 8; i += 256) {
        int row = i >> 3, c8 = i & 7;
        *((uint4*)&Bw[row * 72 + c8 * 8]) = ((const uint4*)c2wT)[(w8 * 64 + row) * 8 + c8];
      }
      __syncthreads();
      #pragma unroll
      for (int ks = 0; ks < 2; ++ks) {
        int kof = ks * 32 + q * 8;
        short8 a[2], bb[4];
        #pragma unroll
        for (int mt = 0; mt < 2; ++mt) {
          int tl = wv + 4 * mt;
          a[mt] = *(const short8*)&l1buf[(tl * 16 + m + w8) * 72 + kof];
        }
        #pragma unroll
        for (int nt = 0; nt < 4; ++nt)
          bb[nt] = *(const short8*)&Bw[(nt * 16 + m) * 72 + kof];
        #pragma unroll
        for (int mt = 0; mt < 2; ++mt)
          #pragma unroll
          for (int nt = 0; nt < 4; ++nt)
            acc2[mt][nt] = __builtin_amdgcn_mfma_f32_16x16x32_bf16(a[mt], bb[nt], acc2[mt][nt], 0, 0, 0);
      }
    }
    #pragma unroll
    for (int mt = 0; mt < 2; ++mt) {
      int tl = wv + 4 * mt;
      #pragma unroll
      for (int nt = 0; nt < 4; ++nt) {
        int c = nt * 16 + m;
        float bs = c2b[c];
        #pragma unroll
        for (int r = 0; r < 4; ++r)
          c2o[(size_t)(b * L_ + l0 + tl * 16 + q * 4 + r) * 64 + c] = f2bf(acc2[mt][nt][r] + bs);
      }
    }
  }
}

// ---------------------------------------------------------------------------
// K5: per-batch tail: L2=c2o*h_t -> l2norm -> conv3 -> softmax alpha ->
//     n_hat = sum alpha*tok -> logits = tok.n_hat + bias -> softmax -> out
// ---------------------------------------------------------------------------
__global__ __launch_bounds__(256) void k_final(
    const unsigned short* __restrict__ tokpad, const unsigned short* __restrict__ c2o,
    const float* __restrict__ h_t, const float* __restrict__ c3w,
    const float* __restrict__ c3b, const float* __restrict__ biasg,
    float* __restrict__ out)
{
  __shared__ float Lf[71 * 65];
  __shared__ float a_lds[2048];
  __shared__ float l_lds[2048];
  __shared__ float red[256];
  __shared__ float nred[512];
  __shared__ float nhat[128];
  __shared__ float ht[64];
  __shared__ float c3[512];
  int b = blockIdx.x, tid = threadIdx.x, lane = tid & 63, wave = tid >> 6;
  if (tid < 64) ht[tid] = h_t[b * 64 + tid];
  for (int i = tid; i < 512; i += 256) c3[i] = c3w[i];
  float c3bias = c3b[0];
  __syncthreads();
  // ---- pass 1: a_logits via normalized features + conv3 (tiles of 64 l) ----
  for (int tile = 0; tile < 32; ++tile) {
    int lt = tile << 6;
    for (int i0 = wave; i0 < 71; i0 += 4) {
      int l = lt - 3 + i0;
      float v = 0.f;
      if (l >= 0 && l < L_) v = bf2f(c2o[((size_t)b * L_ + l) * 64 + lane]) * ht[lane];
      float ss = v * v;
      #pragma unroll
      for (int msk = 1; msk < 64; msk <<= 1) ss += __shfl_xor(ss, msk);
      Lf[i0 * 65 + lane] = v * rsqrtf(ss + 1e-12f);
    }
    __syncthreads();
    {
      int u = lane, part = wave;
      float p = 0.f;
      #pragma unroll
      for (int w = 0; w < 8; ++w)
        #pragma unroll
        for (int cc = 0; cc < 16; ++cc) {
          int c = part * 16 + cc;
          p += Lf[(u + w) * 65 + c] * c3[w * 64 + c];
        }
      red[tid] = p;
    }
    __syncthreads();
    if (tid < 64) a_lds[lt + tid] = red[tid] + red[64 + tid] + red[128 + tid] + red[192 + tid] + c3bias;
    __syncthreads();
  }
  // ---- pass 2: softmax alpha over 2048 ----
  {
    float mx = -1e30f;
    for (int i = tid; i < 2048; i += 256) mx = fmaxf(mx, a_lds[i]);
    #pragma unroll
    for (int msk = 1; msk < 64; msk <<= 1) mx = fmaxf(mx, __shfl_xor(mx, msk));
    if (lane == 0) red[wave] = mx;
    __syncthreads();
    mx = fmaxf(fmaxf(red[0], red[1]), fmaxf(red[2], red[3]));
    float sm = 0.f;
    for (int i = tid; i < 2048; i += 256) sm += __expf(a_lds[i] - mx);
    #pragma unroll
    for (int msk = 1; msk < 64; msk <<= 1) sm += __shfl_xor(sm, msk);
    __syncthreads();
    if (lane == 0) red[wave] = sm;
    __syncthreads();
    sm = red[0] + red[1] + red[2] + red[3];
    float inv = 1.f / sm;
    for (int i = tid; i < 2048; i += 256) a_lds[i] = __expf(a_lds[i] - mx) * inv;
    __syncthreads();
  }
  // ---- pass 3: n_hat[128] = sum_l alpha_l * tok[l][:] ----
  {
    int d2 = tid & 63, g = tid >> 6;
    float ax = 0.f, ay = 0.f;
    for (int l = g; l < L_; l += 4) {
      unsigned int uu = *(const unsigned int*)&tokpad[((size_t)b * LP + PAD + l) * 128 + d2 * 2];
      float al = a_lds[l];
      ax += al * bf2f((unsigned short)(uu & 0xffffu));
      ay += al * bf2f((unsigned short)(uu >> 16));
    }
    nred[g * 128 + d2 * 2] = ax;
    nred[g * 128 + d2 * 2 + 1] = ay;
    __syncthreads();
    if (tid < 128) nhat[tid] = nred[tid] + nred[128 + tid] + nred[256 + tid] + nred[384 + tid];
    __syncthreads();
  }
  // ---- pass 4: logits = tok . n_hat + bias ----
  for (int li = 0; li < 8; ++li) {
    int l = li * 256 + tid;
    const uint4* rowp = (const uint4*)&tokpad[((size_t)b * LP + PAD + l) * 128];
    float s = 0.f;
    #pragma unroll
    for (int jj = 0; jj < 16; ++jj) {
      uint4 uu = rowp[jj];
      s += bf2f((unsigned short)(uu.x & 0xffffu)) * nhat[jj*8+0]
         + bf2f((unsigned short)(uu.x >> 16))     * nhat[jj*8+1]
         + bf2f((unsigned short)(uu.y & 0xffffu)) * nhat[jj*8+2]
         + bf2f((unsigned short)(uu.y >> 16))     * nhat[jj*8+3]
         + bf2f((unsigned short)(uu.z & 0xffffu)) * nhat[jj*8+4]
         + bf2f((unsigned short)(uu.z >> 16))     * nhat[jj*8+5]
         + bf2f((unsigned short)(uu.w & 0xffffu)) * nhat[jj*8+6]
         + bf2f((unsigned short)(uu.w >> 16))     * nhat[jj*8+7];
    }
    l_lds[l] = s + biasg[b * L_ + l];
  }
  __syncthreads();
  // ---- pass 5: final softmax -> out ----
  {
    float mx = -1e30f;
    for (int i = tid; i < 2048; i += 256) mx = fmaxf(mx, l_lds[i]);
    #pragma unroll
    for (int msk = 1; msk < 64; msk <<= 1) mx = fmaxf(mx, __shfl_xor(mx, msk));
    __syncthreads();
    if (lane == 0) red[wave] = mx;
    __syncthreads();
    mx = fmaxf(fmaxf(red[0], red[1]), fmaxf(red[2], red[3]));
    float sm = 0.f;
    for (int i = tid; i < 2048; i += 256) sm += __expf(l_lds[i] - mx);
    #pragma unroll
    for (int msk = 1; msk < 64; msk <<= 1) sm += __shfl_xor(sm, msk);
    __syncthreads();
    if (lane == 0) red[wave] = sm;
    __syncthreads();
    sm = red[0] + red[1] + red[2] + red[3];
    float inv = 1.f / sm;
    for (int i = tid; i < 2048; i += 256) out[b * L_ + i] = __expf(l_lds[i] - mx) * inv;
  }
}

// ---------------------------------------------------------------------------
extern "C" void kernel_launch(void* const* d_in, const int* in_sizes, int n_in,
                              void* d_out, int out_size, void* d_ws, size_t ws_size,
                              hipStream_t stream) {
  const int*   code = (const int*)d_in[0];
  const float* E    = (const float*)d_in[1];
  const float* bt   = (const float*)d_in[2];
  const float* Wx   = (const float*)d_in[3];
  const float* Wh   = (const float*)d_in[4];
  const float* bg   = (const float*)d_in[5];
  const float* c1w  = (const float*)d_in[6];
  const float* c1b  = (const float*)d_in[7];
  const float* c2w  = (const float*)d_in[8];
  const float* c2b  = (const float*)d_in[9];
  const float* c3w  = (const float*)d_in[10];
  const float* c3b  = (const float*)d_in[11];
  char* ws = (char*)d_ws;
  unsigned short* tokpad = (unsigned short*)(ws);               // 33,685,504 B
  unsigned short* xg     = (unsigned short*)(ws + 33685504);    // 67,108,864 B
  unsigned short* c2o    = (unsigned short*)(ws + 100794368);   // 16,777,216 B
  unsigned short* WxT    = (unsigned short*)(ws + 117571584);   //     49,152 B
  unsigned short* c1wT   = (unsigned short*)(ws + 117620736);   //    131,072 B
  unsigned short* c2wT   = (unsigned short*)(ws + 117751808);   //     65,536 B
  float*          htp    = (float*)(ws + 117817344);            //     16,384 B
  float*          biasg  = (float*)(ws + 117833728);            //    524,288 B
  // total ws use: 118,358,016 B

  k_prep <<<9216, 256, 0, stream>>>(code, E, bt, Wx, c1w, c2w, tokpad, WxT, c1wT, c2wT, biasg);
  k_xproj<<<1024, 256, 0, stream>>>(tokpad, WxT, bg, xg);
  k_fused<<<256, 256, 0, stream>>>(xg, Wh, bg, htp, tokpad, c1wT, c1b, c2wT, c2b, c2o);
  k_final<<<64, 256, 0, stream>>>(tokpad, c2o, htp, c3w, c3b, biasg, (float*)d_out);
}

// Round 9
// 1218.999 us; speedup vs baseline: 1.7437x; 1.2419x over previous
//
#include <hip/hip_runtime.h>

#define B_ 64
#define L_ 2048
#define D_ 128
#define LP 2056   // padded rows per batch (3 left, 5 right incl. alignment)
#define PAD 3     // SAME-pad left for W=8

typedef __attribute__((ext_vector_type(8))) short short8;
typedef __attribute__((ext_vector_type(4))) float f32x4;
typedef __attribute__((ext_vector_type(4))) unsigned short us4;

static __device__ __forceinline__ float bf2f(unsigned short u) {
  return __uint_as_float(((unsigned int)u) << 16);
}
static __device__ __forceinline__ unsigned short f2bf(float f) {
  unsigned int x = __float_as_uint(f);
  unsigned int r = (x + 0x7fffu + ((x >> 16) & 1u)) >> 16;  // RNE
  return (unsigned short)r;
}

// ---------------------------------------------------------------------------
// K0: gather tok -> bf16 padded [B,LP,128]; gather bias; transpose weights.
// ---------------------------------------------------------------------------
__global__ __launch_bounds__(256) void k_prep(
    const int* __restrict__ code, const float* __restrict__ E,
    const float* __restrict__ bias_table, const float* __restrict__ Wx,
    const float* __restrict__ c1w, const float* __restrict__ c2w,
    unsigned short* __restrict__ tokpad,
    unsigned short* __restrict__ WxT, unsigned short* __restrict__ c1wT,
    unsigned short* __restrict__ c2wT, float* __restrict__ biasg)
{
  int id = blockIdx.x * 256 + threadIdx.x;
  const int N0 = B_ * LP * 16;            // tokpad in uint4 (8 bf16) chunks
  if (id < N0) {
    int b = id / (LP * 16); int rem = id % (LP * 16);
    int row = rem >> 4, c8 = rem & 15;
    uint4 o = {0u,0u,0u,0u};
    if (row >= PAD && row < PAD + L_) {
      int cd = code[b * L_ + (row - PAD)];
      const float4* e = (const float4*)(E + (size_t)cd * D_ + c8 * 8);
      float4 e0 = e[0], e1 = e[1];
      o.x = f2bf(e0.x) | ((unsigned int)f2bf(e0.y) << 16);
      o.y = f2bf(e0.z) | ((unsigned int)f2bf(e0.w) << 16);
      o.z = f2bf(e1.x) | ((unsigned int)f2bf(e1.y) << 16);
      o.w = f2bf(e1.z) | ((unsigned int)f2bf(e1.w) << 16);
    }
    ((uint4*)tokpad)[id] = o;
    return;
  }
  id -= N0;
  const int N2 = B_ * L_;
  if (id < N2) { biasg[id] = bias_table[code[id]]; return; }
  id -= N2;
  const int N3 = 192 * 128;               // WxT[c][d]
  if (id < N3) { int c = id >> 7, d = id & 127; WxT[id] = f2bf(Wx[d * 192 + c]); return; }
  id -= N3;
  const int N4 = 8 * 64 * 128;            // c1wT[w][c][d]
  if (id < N4) {
    int w = id >> 13, c = (id >> 7) & 63, d = id & 127;
    c1wT[id] = f2bf(c1w[(w * 128 + d) * 64 + c]); return;
  }
  id -= N4;
  const int N5 = 8 * 64 * 64;             // c2wT[w][c][d]
  if (id < N5) {
    int w = id >> 12, c = (id >> 6) & 63, d = id & 63;
    c2wT[id] = f2bf(c2w[(w * 64 + d) * 64 + c]);
  }
}

// ---------------------------------------------------------------------------
// K1: x_proj = tok @ Wx + b_gru[0] -> bf16, GATE-INTERLEAVED per lane:
// xg[b][j][t][{z,r,h,0}] (8 B per step). Same C bits as the R10 kernel
// (same acc, same f2bf); only placement changed so a GRU lane reads ONE
// stream (uint4 = 2 steps).
// ---------------------------------------------------------------------------
__global__ __launch_bounds__(256) void k_xproj(
    const unsigned short* __restrict__ tokpad, const unsigned short* __restrict__ WxT,
    const float* __restrict__ bg, unsigned short* __restrict__ xg)
{
  __shared__ __align__(16) unsigned short At[128 * 136];
  __shared__ __align__(16) unsigned short Bt[192 * 136];
  int b = blockIdx.x >> 4;
  int l0 = (blockIdx.x & 15) << 7;
  int tid = threadIdx.x;
  for (int i = tid; i < 128 * 16; i += 256) {
    int row = i >> 4, c8 = i & 15;
    uint4 v = ((const uint4*)tokpad)[(b * LP + PAD + l0 + row) * 16 + c8];
    *((uint4*)&At[row * 136 + c8 * 8]) = v;
  }
  for (int i = tid; i < 192 * 16; i += 256) {
    int row = i >> 4, c8 = i & 15;
    uint4 v = ((const uint4*)WxT)[i];
    *((uint4*)&Bt[row * 136 + c8 * 8]) = v;
  }
  __syncthreads();
  int wave = tid >> 6, lane = tid & 63;
  int m = lane & 15, q = lane >> 4;
  f32x4 acc[2][12];
  #pragma unroll
  for (int mt = 0; mt < 2; ++mt)
    #pragma unroll
    for (int nt = 0; nt < 12; ++nt) acc[mt][nt] = (f32x4){0.f,0.f,0.f,0.f};
  #pragma unroll
  for (int ks = 0; ks < 4; ++ks) {
    int kof = ks * 32 + q * 8;
    short8 a[2], bb[12];
    #pragma unroll
    for (int mt = 0; mt < 2; ++mt)
      a[mt] = *(const short8*)&At[(wave * 32 + mt * 16 + m) * 136 + kof];
    #pragma unroll
    for (int nt = 0; nt < 12; ++nt)
      bb[nt] = *(const short8*)&Bt[(nt * 16 + m) * 136 + kof];
    #pragma unroll
    for (int mt = 0; mt < 2; ++mt)
      #pragma unroll
      for (int nt = 0; nt < 12; ++nt)
        acc[mt][nt] = __builtin_amdgcn_mfma_f32_16x16x32_bf16(a[mt], bb[nt], acc[mt][nt], 0, 0, 0);
  }
  __syncthreads();                        // all MFMA reads of Bt done
  // deposit C (+bias, bf16) transposed into Bt[c][l]  (l = 0..127)
  #pragma unroll
  for (int mt = 0; mt < 2; ++mt) {
    int lrow = wave * 32 + mt * 16 + q * 4;
    #pragma unroll
    for (int nt = 0; nt < 12; ++nt) {
      int c = nt * 16 + m;                 // C col = lane&15
      float b0 = bg[c];
      us4 val;
      val.x = f2bf(acc[mt][nt][0] + b0);
      val.y = f2bf(acc[mt][nt][1] + b0);
      val.z = f2bf(acc[mt][nt][2] + b0);
      val.w = f2bf(acc[mt][nt][3] + b0);
      *((us4*)&Bt[c * 136 + lrow]) = val;
    }
  }
  __syncthreads();
  // gate-interleaved write-out: per (j, 4-step group): read z/r/h 4-wide,
  // pack [z|r<<16, h] per step, store 2 x uint4 (32 B contiguous per lane).
  for (int i = tid; i < 64 * 32; i += 256) {
    int j = i >> 5, g = i & 31;           // steps l = 4g..4g+3
    us4 z4 = *(const us4*)&Bt[j * 136 + g * 4];
    us4 r4 = *(const us4*)&Bt[(64 + j) * 136 + g * 4];
    us4 h4 = *(const us4*)&Bt[(128 + j) * 136 + g * 4];
    uint4 o0, o1;
    o0.x = (unsigned)z4.x | ((unsigned)r4.x << 16); o0.y = (unsigned)h4.x;
    o0.z = (unsigned)z4.y | ((unsigned)r4.y << 16); o0.w = (unsigned)h4.y;
    o1.x = (unsigned)z4.z | ((unsigned)r4.z << 16); o1.y = (unsigned)h4.z;
    o1.z = (unsigned)z4.w | ((unsigned)r4.w << 16); o1.w = (unsigned)h4.w;
    size_t stp = (size_t)(b * 64 + j) * L_ + l0 + g * 4;  // step index
    ((uint4*)xg)[stp >> 1]       = o0;
    ((uint4*)xg)[(stp >> 1) + 1] = o1;
  }
}

// ---------------------------------------------------------------------------
// K2 (fused): blocks 0..63 = GRU scan; blocks 64..255 = conv1+conv2 with
// halo recompute (l1 LDS-only, identical bf16 rounding). No cross-block deps.
//
// R19: k_fused reverted VERBATIM to R16 (best measured: 904 us, T_step
// ~1059 cyc). R18's 4-wave split proved the issue-width lever is exhausted
// (1085 cyc despite -90 cyc issue): the floor is exchange+barrier+tanh-tail
// latency. 3-wave k-split + readlane h-broadcast stands.
// ---------------------------------------------------------------------------
#define BARRIER() asm volatile("s_waitcnt lgkmcnt(0)\n\ts_barrier" ::: "memory")

__global__ __launch_bounds__(192)
__attribute__((amdgpu_waves_per_eu(1, 1)))
void k_fused(
    const unsigned short* __restrict__ xg, const float* __restrict__ Wh,
    const float* __restrict__ bg, float* __restrict__ h_t,
    const unsigned short* __restrict__ tokpad,
    const unsigned short* __restrict__ c1wT, const float* __restrict__ c1b,
    const unsigned short* __restrict__ c2wT, const float* __restrict__ c2b,
    unsigned short* __restrict__ c2o)
{
  __shared__ __align__(16) unsigned short pool[39744];
  int bid = blockIdx.x;
  int tid = threadIdx.x;

  if (bid < 64) {
    // ================= GRU scan (R16: 3-wave k-split, readlane h) ========
    int w = tid >> 6, j = tid & 63;
    float* xch = (float*)pool;            // 2 parities x 3 waves x 64 x f32x4
    int b = bid;
    int kb = w * 22;                      // k-rows kb..kb+21 (padded past 63)

    float wz[22], wr[22], wh[22];
    #pragma unroll
    for (int i = 0; i < 22; ++i) {
      int k = kb + i;
      bool ok = k < 64;
      wz[i] = ok ? Wh[k * 192 + j]       : 0.f;
      wr[i] = ok ? Wh[k * 192 + 64 + j]  : 0.f;
      wh[i] = ok ? Wh[k * 192 + 128 + j] : 0.f;
    }
    #pragma unroll
    for (int i = 0; i < 22; ++i)
      asm volatile("" : "+v"(wz[i]), "+v"(wr[i]), "+v"(wh[i]));

    // bias seeds: only wave 0 carries the bias (fixed-order partial sum).
    float seedz = (w == 0) ? bg[192 + j]       : 0.f;
    float seedr = (w == 0) ? bg[192 + 64 + j]  : 0.f;
    float seedh = (w == 0) ? bg[192 + 128 + j] : 0.f;
    float hreg = 0.f;

    const uint4* xp = (const uint4*)(xg + (size_t)(b * 64 + j) * L_ * 4);
    uint4 cur_ = xp[0];
    uint4 nxt_ = xp[1];

#define STEP(WZR, WH_, P) { \
    float hk[22]; \
    _Pragma("unroll") \
    for (int i = 0; i < 22; ++i) \
      hk[i] = __int_as_float(__builtin_amdgcn_readlane(__float_as_int(hreg), (kb + i) & 63)); \
    __builtin_amdgcn_sched_barrier(0); \
    float az[4] = {seedz, 0.f, 0.f, 0.f}; \
    float ar[4] = {seedr, 0.f, 0.f, 0.f}; \
    float ah[4] = {seedh, 0.f, 0.f, 0.f}; \
    _Pragma("unroll") \
    for (int i = 0; i < 22; ++i) { \
      az[i & 3] = fmaf(hk[i], wz[i], az[i & 3]); \
      ar[i & 3] = fmaf(hk[i], wr[i], ar[i & 3]); \
      ah[i & 3] = fmaf(hk[i], wh[i], ah[i & 3]); \
    } \
    float4 pv; \
    pv.x = (az[0] + az[1]) + (az[2] + az[3]); \
    pv.y = (ar[0] + ar[1]) + (ar[2] + ar[3]); \
    pv.z = (ah[0] + ah[1]) + (ah[2] + ah[3]); \
    pv.w = 0.f; \
    *((float4*)&xch[(P) * 768 + (w * 64 + j) * 4]) = pv; \
    BARRIER(); \
    float4 q0 = *((const float4*)&xch[(P) * 768 + (0 * 64 + j) * 4]); \
    float4 q1 = *((const float4*)&xch[(P) * 768 + (1 * 64 + j) * 4]); \
    float4 q2 = *((const float4*)&xch[(P) * 768 + (2 * 64 + j) * 4]); \
    float sz = (q0.x + q1.x) + q2.x; \
    float sr = (q0.y + q1.y) + q2.y; \
    float sh = (q0.z + q1.z) + q2.z; \
    float xvz = bf2f((unsigned short)((WZR) & 0xffffu)); \
    float xvr = bf2f((unsigned short)((WZR) >> 16)); \
    float xvh = bf2f((unsigned short)((WH_) & 0xffffu)); \
    float zg = 1.f / (1.f + __expf(-(xvz + sz))); \
    float rg = 1.f / (1.f + __expf(-(xvr + sr))); \
    float e2 = __expf(-2.f * (xvh + rg * sh)); \
    float hh = fmaf(2.f, __frcp_rn(1.f + e2), -1.f); \
    hreg = zg * hreg + (1.f - zg) * hh; \
  }

    #pragma nounroll
    for (int p = 0; p < L_ / 2; ++p) {
      int pn = (p < L_ / 2 - 2) ? p + 2 : (L_ / 2 - 1);
      uint4 nn = xp[pn];
      STEP(cur_.x, cur_.y, 0)
      STEP(cur_.z, cur_.w, 1)
      cur_ = nxt_; nxt_ = nn;
    }
#undef STEP
    if (w == 0) h_t[b * 64 + j] = hreg;
    return;
  }

  // ================= fused conv1+conv2 (halo recompute) =================
  unsigned short* At    = pool;           // 152 x 136 shorts = 41344 B
  unsigned short* l1buf = pool + 20672;   // 144 x 72  shorts = 20736 B
  unsigned short* Bw    = pool + 31040;   //  64 x 136 shorts = 17408 B
  int wv = tid >> 6, lane = tid & 63;
  int m = lane & 15, q = lane >> 4;

  for (int job = bid - 64; job < 1024; job += 192) {
    int b = job >> 4;
    int l0 = (job & 15) << 7;
    __syncthreads();                      // prev job fully consumed
    for (int i = tid; i < 152 * 16; i += 192) {
      int row = i >> 4, c8 = i & 15;
      int p = l0 - 3 + row;
      p = p < 0 ? 0 : (p > 2055 ? 2055 : p);
      *((uint4*)&At[row * 136 + c8 * 8]) = ((const uint4*)tokpad)[(b * LP + p) * 16 + c8];
    }
    // ---- conv1: l1 rows [l0-3, l0+140] (9 M-tiles of 16), K=128 ----
    f32x4 acc[3][4];
    #pragma unroll
    for (int mt = 0; mt < 3; ++mt)
      #pragma unroll
      for (int nt = 0; nt < 4; ++nt) acc[mt][nt] = (f32x4){0.f,0.f,0.f,0.f};
    for (int w8 = 0; w8 < 8; ++w8) {
      __syncthreads();
      for (int i = tid; i < 64 * 16; i += 192) {
        int row = i >> 4, c8 = i & 15;
        *((uint4*)&Bw[row * 136 + c8 * 8]) = ((const uint4*)c1wT)[(w8 * 64 + row) * 16 + c8];
      }
      __syncthreads();
      #pragma unroll
      for (int ks = 0; ks < 4; ++ks) {
        int kof = ks * 32 + q * 8;
        short8 a[3], bb[4];
        #pragma unroll
        for (int mt = 0; mt < 3; ++mt) {
          int tl = wv + 3 * mt;
          a[mt] = *(const short8*)&At[(tl * 16 + m + w8) * 136 + kof];
        }
        #pragma unroll
        for (int nt = 0; nt < 4; ++nt)
          bb[nt] = *(const short8*)&Bw[(nt * 16 + m) * 136 + kof];
        #pragma unroll
        for (int mt = 0; mt < 3; ++mt)
          #pragma unroll
          for (int nt = 0; nt < 4; ++nt)
            acc[mt][nt] = __builtin_amdgcn_mfma_f32_16x16x32_bf16(a[mt], bb[nt], acc[mt][nt], 0, 0, 0);
      }
    }
    #pragma unroll
    for (int mt = 0; mt < 3; ++mt) {
      int tl = wv + 3 * mt;
      #pragma unroll
      for (int nt = 0; nt < 4; ++nt) {
        int c = nt * 16 + m;
        float bs = c1b[c];
        #pragma unroll
        for (int r = 0; r < 4; ++r) {
          float v = fmaxf(acc[mt][nt][r] + bs, 0.f);
          l1buf[(tl * 16 + q * 4 + r) * 72 + c] = f2bf(v);
        }
      }
    }
    __syncthreads();
    for (int i2 = tid; i2 < 135 * 8; i2 += 192) {
      int i = i2 >> 3, c8 = i2 & 7;
      int jrow = l0 - 3 + i;
      if (jrow < 0 || jrow > 2047) {
        uint4 z4 = {0u,0u,0u,0u};
        *((uint4*)&l1buf[i * 72 + c8 * 8]) = z4;
      }
    }
    // ---- conv2: out rows [l0, l0+127] (8 M-tiles), K=64 ----
    f32x4 acc2[3][4];
    #pragma unroll
    for (int mt = 0; mt < 3; ++mt)
      #pragma unroll
      for (int nt = 0; nt < 4; ++nt) acc2[mt][nt] = (f32x4){0.f,0.f,0.f,0.f};
    for (int w8 = 0; w8 < 8; ++w8) {
      __syncthreads();
      for (int i = tid; i < 64 * 8; i += 192) {
        int row = i >> 3, c8 = i & 7;
        *((uint4*)&Bw[row * 72 + c8 * 8]) = ((const uint4*)c2wT)[(w8 * 64 + row) * 8 + c8];
      }
      __syncthreads();
      #pragma unroll
      for (int ks = 0; ks < 2; ++ks) {
        int kof = ks * 32 + q * 8;
        short8 a[3], bb[4];
        #pragma unroll
        for (int mt = 0; mt < 3; ++mt) {
          int tl = wv + 3 * mt;
          if (tl < 8)
            a[mt] = *(const short8*)&l1buf[(tl * 16 + m + w8) * 72 + kof];
        }
        #pragma unroll
        for (int nt = 0; nt < 4; ++nt)
          bb[nt] = *(const short8*)&Bw[(nt * 16 + m) * 72 + kof];
        #pragma unroll
        for (int mt = 0; mt < 3; ++mt) {
          int tl = wv + 3 * mt;
          if (tl < 8)
            #pragma unroll
            for (int nt = 0; nt < 4; ++nt)
              acc2[mt][nt] = __builtin_amdgcn_mfma_f32_16x16x32_bf16(a[mt], bb[nt], acc2[mt][nt], 0, 0, 0);
        }
      }
    }
    #pragma unroll
    for (int mt = 0; mt < 3; ++mt) {
      int tl = wv + 3 * mt;
      if (tl < 8) {
        #pragma unroll
        for (int nt = 0; nt < 4; ++nt) {
          int c = nt * 16 + m;
          float bs = c2b[c];
          #pragma unroll
          for (int r = 0; r < 4; ++r)
            c2o[(size_t)(b * L_ + l0 + tl * 16 + q * 4 + r) * 64 + c] = f2bf(acc2[mt][nt][r] + bs);
        }
      }
    }
  }
}

// ---------------------------------------------------------------------------
// K3 (R19 new): a_logits, one block per (batch, 64-l tile). The old k_final
// pass 1 ran these 32 tiles SERIALLY per block on a 64-block grid (25% of
// CUs); here the same tile body (verbatim op order -> identical bits) runs
// on 2048 blocks. Output reuses xg's ws space (xg dead after k_fused).
// ---------------------------------------------------------------------------
__global__ __launch_bounds__(256) void k_alpha(
    const unsigned short* __restrict__ c2o, const float* __restrict__ h_t,
    const float* __restrict__ c3w, const float* __restrict__ c3b,
    float* __restrict__ a_out)
{
  __shared__ float Lf[71 * 65];
  __shared__ float red[256];
  __shared__ float ht[64];
  __shared__ float c3[512];
  int b = blockIdx.x >> 5;
  int tile = blockIdx.x & 31;
  int tid = threadIdx.x, lane = tid & 63, wave = tid >> 6;
  if (tid < 64) ht[tid] = h_t[b * 64 + tid];
  for (int i = tid; i < 512; i += 256) c3[i] = c3w[i];
  float c3bias = c3b[0];
  __syncthreads();
  int lt = tile << 6;
  for (int i0 = wave; i0 < 71; i0 += 4) {
    int l = lt - 3 + i0;
    float v = 0.f;
    if (l >= 0 && l < L_) v = bf2f(c2o[((size_t)b * L_ + l) * 64 + lane]) * ht[lane];
    float ss = v * v;
    #pragma unroll
    for (int msk = 1; msk < 64; msk <<= 1) ss += __shfl_xor(ss, msk);
    Lf[i0 * 65 + lane] = v * rsqrtf(ss + 1e-12f);
  }
  __syncthreads();
  {
    int u = lane, part = wave;
    float p = 0.f;
    #pragma unroll
    for (int w = 0; w < 8; ++w)
      #pragma unroll
      for (int cc = 0; cc < 16; ++cc) {
        int c = part * 16 + cc;
        p += Lf[(u + w) * 65 + c] * c3[w * 64 + c];
      }
    red[tid] = p;
  }
  __syncthreads();
  if (tid < 64)
    a_out[b * L_ + lt + tid] = red[tid] + red[64 + tid] + red[128 + tid] + red[192 + tid] + c3bias;
}

// ---------------------------------------------------------------------------
// K4 (R19): former k_final passes 2..5 (verbatim); a_logits read from ws.
// ---------------------------------------------------------------------------
__global__ __launch_bounds__(256) void k_fin(
    const unsigned short* __restrict__ tokpad, const float* __restrict__ a_in,
    const float* __restrict__ biasg, float* __restrict__ out)
{
  __shared__ float a_lds[2048];
  __shared__ float l_lds[2048];
  __shared__ float red[256];
  __shared__ float nred[512];
  __shared__ float nhat[128];
  int b = blockIdx.x, tid = threadIdx.x, lane = tid & 63, wave = tid >> 6;
  for (int i = tid; i < 2048; i += 256) a_lds[i] = a_in[b * L_ + i];
  __syncthreads();
  // ---- pass 2: softmax alpha over 2048 ----
  {
    float mx = -1e30f;
    for (int i = tid; i < 2048; i += 256) mx = fmaxf(mx, a_lds[i]);
    #pragma unroll
    for (int msk = 1; msk < 64; msk <<= 1) mx = fmaxf(mx, __shfl_xor(mx, msk));
    if (lane == 0) red[wave] = mx;
    __syncthreads();
    mx = fmaxf(fmaxf(red[0], red[1]), fmaxf(red[2], red[3]));
    float sm = 0.f;
    for (int i = tid; i < 2048; i += 256) sm += __expf(a_lds[i] - mx);
    #pragma unroll
    for (int msk = 1; msk < 64; msk <<= 1) sm += __shfl_xor(sm, msk);
    __syncthreads();
    if (lane == 0) red[wave] = sm;
    __syncthreads();
    sm = red[0] + red[1] + red[2] + red[3];
    float inv = 1.f / sm;
    for (int i = tid; i < 2048; i += 256) a_lds[i] = __expf(a_lds[i] - mx) * inv;
    __syncthreads();
  }
  // ---- pass 3: n_hat[128] = sum_l alpha_l * tok[l][:] ----
  {
    int d2 = tid & 63, g = tid >> 6;
    float ax = 0.f, ay = 0.f;
    for (int l = g; l < L_; l += 4) {
      unsigned int uu = *(const unsigned int*)&tokpad[((size_t)b * LP + PAD + l) * 128 + d2 * 2];
      float al = a_lds[l];
      ax += al * bf2f((unsigned short)(uu & 0xffffu));
      ay += al * bf2f((unsigned short)(uu >> 16));
    }
    nred[g * 128 + d2 * 2] = ax;
    nred[g * 128 + d2 * 2 + 1] = ay;
    __syncthreads();
    if (tid < 128) nhat[tid] = nred[tid] + nred[128 + tid] + nred[256 + tid] + nred[384 + tid];
    __syncthreads();
  }
  // ---- pass 4: logits = tok . n_hat + bias ----
  for (int li = 0; li < 8; ++li) {
    int l = li * 256 + tid;
    const uint4* rowp = (const uint4*)&tokpad[((size_t)b * LP + PAD + l) * 128];
    float s = 0.f;
    #pragma unroll
    for (int jj = 0; jj < 16; ++jj) {
      uint4 uu = rowp[jj];
      s += bf2f((unsigned short)(uu.x & 0xffffu)) * nhat[jj*8+0]
         + bf2f((unsigned short)(uu.x >> 16))     * nhat[jj*8+1]
         + bf2f((unsigned short)(uu.y & 0xffffu)) * nhat[jj*8+2]
         + bf2f((unsigned short)(uu.y >> 16))     * nhat[jj*8+3]
         + bf2f((unsigned short)(uu.z & 0xffffu)) * nhat[jj*8+4]
         + bf2f((unsigned short)(uu.z >> 16))     * nhat[jj*8+5]
         + bf2f((unsigned short)(uu.w & 0xffffu)) * nhat[jj*8+6]
         + bf2f((unsigned short)(uu.w >> 16))     * nhat[jj*8+7];
    }
    l_lds[l] = s + biasg[b * L_ + l];
  }
  __syncthreads();
  // ---- pass 5: final softmax -> out ----
  {
    float mx = -1e30f;
    for (int i = tid; i < 2048; i += 256) mx = fmaxf(mx, l_lds[i]);
    #pragma unroll
    for (int msk = 1; msk < 64; msk <<= 1) mx = fmaxf(mx, __shfl_xor(mx, msk));
    __syncthreads();
    if (lane == 0) red[wave] = mx;
    __syncthreads();
    mx = fmaxf(fmaxf(red[0], red[1]), fmaxf(red[2], red[3]));
    float sm = 0.f;
    for (int i = tid; i < 2048; i += 256) sm += __expf(l_lds[i] - mx);
    #pragma unroll
    for (int msk = 1; msk < 64; msk <<= 1) sm += __shfl_xor(sm, msk);
    __syncthreads();
    if (lane == 0) red[wave] = sm;
    __syncthreads();
    sm = red[0] + red[1] + red[2] + red[3];
    float inv = 1.f / sm;
    for (int i = tid; i < 2048; i += 256) out[b * L_ + i] = __expf(l_lds[i] - mx) * inv;
  }
}

// ---------------------------------------------------------------------------
extern "C" void kernel_launch(void* const* d_in, const int* in_sizes, int n_in,
                              void* d_out, int out_size, void* d_ws, size_t ws_size,
                              hipStream_t stream) {
  const int*   code = (const int*)d_in[0];
  const float* E    = (const float*)d_in[1];
  const float* bt   = (const float*)d_in[2];
  const float* Wx   = (const float*)d_in[3];
  const float* Wh   = (const float*)d_in[4];
  const float* bg   = (const float*)d_in[5];
  const float* c1w  = (const float*)d_in[6];
  const float* c1b  = (const float*)d_in[7];
  const float* c2w  = (const float*)d_in[8];
  const float* c2b  = (const float*)d_in[9];
  const float* c3w  = (const float*)d_in[10];
  const float* c3b  = (const float*)d_in[11];
  char* ws = (char*)d_ws;
  unsigned short* tokpad = (unsigned short*)(ws);               // 33,685,504 B
  unsigned short* xg     = (unsigned short*)(ws + 33685504);    // 67,108,864 B
  unsigned short* c2o    = (unsigned short*)(ws + 100794368);   // 16,777,216 B
  unsigned short* WxT    = (unsigned short*)(ws + 117571584);   //     49,152 B
  unsigned short* c1wT   = (unsigned short*)(ws + 117620736);   //    131,072 B
  unsigned short* c2wT   = (unsigned short*)(ws + 117751808);   //     65,536 B
  float*          htp    = (float*)(ws + 117817344);            //     16,384 B
  float*          biasg  = (float*)(ws + 117833728);            //    524,288 B
  float*          alog   = (float*)(ws + 33685504);             // reuse xg (dead after k_fused)
  // total ws use: 118,358,016 B

  k_prep <<<9216, 256, 0, stream>>>(code, E, bt, Wx, c1w, c2w, tokpad, WxT, c1wT, c2wT, biasg);
  k_xproj<<<1024, 256, 0, stream>>>(tokpad, WxT, bg, xg);
  k_fused<<<256, 192, 0, stream>>>(xg, Wh, bg, htp, tokpad, c1wT, c1b, c2wT, c2b, c2o);
  k_alpha<<<2048, 256, 0, stream>>>(c2o, htp, c3w, c3b, alog);
  k_fin  <<<64, 256, 0, stream>>>(tokpad, alog, biasg, (float*)d_out);
}

// Round 10
// 1079.258 us; speedup vs baseline: 1.9695x; 1.1295x over previous
//
#include <hip/hip_runtime.h>

#define B_ 64
#define L_ 2048
#define D_ 128
#define LP 2056   // padded rows per batch (3 left, 5 right incl. alignment)
#define PAD 3     // SAME-pad left for W=8

typedef __attribute__((ext_vector_type(8))) short short8;
typedef __attribute__((ext_vector_type(4))) float f32x4;
typedef __attribute__((ext_vector_type(4))) unsigned short us4;

static __device__ __forceinline__ float bf2f(unsigned short u) {
  return __uint_as_float(((unsigned int)u) << 16);
}
static __device__ __forceinline__ unsigned short f2bf(float f) {
  unsigned int x = __float_as_uint(f);
  unsigned int r = (x + 0x7fffu + ((x >> 16) & 1u)) >> 16;  // RNE
  return (unsigned short)r;
}

// ---------------------------------------------------------------------------
// K0: gather tok -> bf16 padded [B,LP,128]; gather bias; transpose weights.
// ---------------------------------------------------------------------------
__global__ __launch_bounds__(256) void k_prep(
    const int* __restrict__ code, const float* __restrict__ E,
    const float* __restrict__ bias_table, const float* __restrict__ Wx,
    const float* __restrict__ c1w, const float* __restrict__ c2w,
    unsigned short* __restrict__ tokpad,
    unsigned short* __restrict__ WxT, unsigned short* __restrict__ c1wT,
    unsigned short* __restrict__ c2wT, float* __restrict__ biasg)
{
  int id = blockIdx.x * 256 + threadIdx.x;
  const int N0 = B_ * LP * 16;            // tokpad in uint4 (8 bf16) chunks
  if (id < N0) {
    int b = id / (LP * 16); int rem = id % (LP * 16);
    int row = rem >> 4, c8 = rem & 15;
    uint4 o = {0u,0u,0u,0u};
    if (row >= PAD && row < PAD + L_) {
      int cd = code[b * L_ + (row - PAD)];
      const float4* e = (const float4*)(E + (size_t)cd * D_ + c8 * 8);
      float4 e0 = e[0], e1 = e[1];
      o.x = f2bf(e0.x) | ((unsigned int)f2bf(e0.y) << 16);
      o.y = f2bf(e0.z) | ((unsigned int)f2bf(e0.w) << 16);
      o.z = f2bf(e1.x) | ((unsigned int)f2bf(e1.y) << 16);
      o.w = f2bf(e1.z) | ((unsigned int)f2bf(e1.w) << 16);
    }
    ((uint4*)tokpad)[id] = o;
    return;
  }
  id -= N0;
  const int N2 = B_ * L_;
  if (id < N2) { biasg[id] = bias_table[code[id]]; return; }
  id -= N2;
  const int N3 = 192 * 128;               // WxT[c][d]
  if (id < N3) { int c = id >> 7, d = id & 127; WxT[id] = f2bf(Wx[d * 192 + c]); return; }
  id -= N3;
  const int N4 = 8 * 64 * 128;            // c1wT[w][c][d]
  if (id < N4) {
    int w = id >> 13, c = (id >> 7) & 63, d = id & 127;
    c1wT[id] = f2bf(c1w[(w * 128 + d) * 64 + c]); return;
  }
  id -= N4;
  const int N5 = 8 * 64 * 64;             // c2wT[w][c][d]
  if (id < N5) {
    int w = id >> 12, c = (id >> 6) & 63, d = id & 63;
    c2wT[id] = f2bf(c2w[(w * 64 + d) * 64 + c]);
  }
}

// ---------------------------------------------------------------------------
// K1: x_proj = tok @ Wx + b_gru[0] -> bf16, GATE-INTERLEAVED per lane:
// xg[b][j][t][{z,r,h,0}] (8 B per step).
// ---------------------------------------------------------------------------
__global__ __launch_bounds__(256) void k_xproj(
    const unsigned short* __restrict__ tokpad, const unsigned short* __restrict__ WxT,
    const float* __restrict__ bg, unsigned short* __restrict__ xg)
{
  __shared__ __align__(16) unsigned short At[128 * 136];
  __shared__ __align__(16) unsigned short Bt[192 * 136];
  int b = blockIdx.x >> 4;
  int l0 = (blockIdx.x & 15) << 7;
  int tid = threadIdx.x;
  for (int i = tid; i < 128 * 16; i += 256) {
    int row = i >> 4, c8 = i & 15;
    uint4 v = ((const uint4*)tokpad)[(b * LP + PAD + l0 + row) * 16 + c8];
    *((uint4*)&At[row * 136 + c8 * 8]) = v;
  }
  for (int i = tid; i < 192 * 16; i += 256) {
    int row = i >> 4, c8 = i & 15;
    uint4 v = ((const uint4*)WxT)[i];
    *((uint4*)&Bt[row * 136 + c8 * 8]) = v;
  }
  __syncthreads();
  int wave = tid >> 6, lane = tid & 63;
  int m = lane & 15, q = lane >> 4;
  f32x4 acc[2][12];
  #pragma unroll
  for (int mt = 0; mt < 2; ++mt)
    #pragma unroll
    for (int nt = 0; nt < 12; ++nt) acc[mt][nt] = (f32x4){0.f,0.f,0.f,0.f};
  #pragma unroll
  for (int ks = 0; ks < 4; ++ks) {
    int kof = ks * 32 + q * 8;
    short8 a[2], bb[12];
    #pragma unroll
    for (int mt = 0; mt < 2; ++mt)
      a[mt] = *(const short8*)&At[(wave * 32 + mt * 16 + m) * 136 + kof];
    #pragma unroll
    for (int nt = 0; nt < 12; ++nt)
      bb[nt] = *(const short8*)&Bt[(nt * 16 + m) * 136 + kof];
    #pragma unroll
    for (int mt = 0; mt < 2; ++mt)
      #pragma unroll
      for (int nt = 0; nt < 12; ++nt)
        acc[mt][nt] = __builtin_amdgcn_mfma_f32_16x16x32_bf16(a[mt], bb[nt], acc[mt][nt], 0, 0, 0);
  }
  __syncthreads();                        // all MFMA reads of Bt done
  // deposit C (+bias, bf16) transposed into Bt[c][l]  (l = 0..127)
  #pragma unroll
  for (int mt = 0; mt < 2; ++mt) {
    int lrow = wave * 32 + mt * 16 + q * 4;
    #pragma unroll
    for (int nt = 0; nt < 12; ++nt) {
      int c = nt * 16 + m;                 // C col = lane&15
      float b0 = bg[c];
      us4 val;
      val.x = f2bf(acc[mt][nt][0] + b0);
      val.y = f2bf(acc[mt][nt][1] + b0);
      val.z = f2bf(acc[mt][nt][2] + b0);
      val.w = f2bf(acc[mt][nt][3] + b0);
      *((us4*)&Bt[c * 136 + lrow]) = val;
    }
  }
  __syncthreads();
  // gate-interleaved write-out: per (j, 4-step group): read z/r/h 4-wide,
  // pack [z|r<<16, h] per step, store 2 x uint4 (32 B contiguous per lane).
  for (int i = tid; i < 64 * 32; i += 256) {
    int j = i >> 5, g = i & 31;           // steps l = 4g..4g+3
    us4 z4 = *(const us4*)&Bt[j * 136 + g * 4];
    us4 r4 = *(const us4*)&Bt[(64 + j) * 136 + g * 4];
    us4 h4 = *(const us4*)&Bt[(128 + j) * 136 + g * 4];
    uint4 o0, o1;
    o0.x = (unsigned)z4.x | ((unsigned)r4.x << 16); o0.y = (unsigned)h4.x;
    o0.z = (unsigned)z4.y | ((unsigned)r4.y << 16); o0.w = (unsigned)h4.y;
    o1.x = (unsigned)z4.z | ((unsigned)r4.z << 16); o1.y = (unsigned)h4.z;
    o1.z = (unsigned)z4.w | ((unsigned)r4.w << 16); o1.w = (unsigned)h4.w;
    size_t stp = (size_t)(b * 64 + j) * L_ + l0 + g * 4;  // step index
    ((uint4*)xg)[stp >> 1]       = o0;
    ((uint4*)xg)[(stp >> 1) + 1] = o1;
  }
}

// ---------------------------------------------------------------------------
// K2 (fused): blocks 0..63 = GRU scan; blocks 64..255 = conv1+conv2 with
// halo recompute. VERBATIM from R16/R19 (best measured: ~905 us).
// ---------------------------------------------------------------------------
#define BARRIER() asm volatile("s_waitcnt lgkmcnt(0)\n\ts_barrier" ::: "memory")

__global__ __launch_bounds__(192)
__attribute__((amdgpu_waves_per_eu(1, 1)))
void k_fused(
    const unsigned short* __restrict__ xg, const float* __restrict__ Wh,
    const float* __restrict__ bg, float* __restrict__ h_t,
    const unsigned short* __restrict__ tokpad,
    const unsigned short* __restrict__ c1wT, const float* __restrict__ c1b,
    const unsigned short* __restrict__ c2wT, const float* __restrict__ c2b,
    unsigned short* __restrict__ c2o)
{
  __shared__ __align__(16) unsigned short pool[39744];
  int bid = blockIdx.x;
  int tid = threadIdx.x;

  if (bid < 64) {
    // ================= GRU scan (R16: 3-wave k-split, readlane h) ========
    int w = tid >> 6, j = tid & 63;
    float* xch = (float*)pool;            // 2 parities x 3 waves x 64 x f32x4
    int b = bid;
    int kb = w * 22;                      // k-rows kb..kb+21 (padded past 63)

    float wz[22], wr[22], wh[22];
    #pragma unroll
    for (int i = 0; i < 22; ++i) {
      int k = kb + i;
      bool ok = k < 64;
      wz[i] = ok ? Wh[k * 192 + j]       : 0.f;
      wr[i] = ok ? Wh[k * 192 + 64 + j]  : 0.f;
      wh[i] = ok ? Wh[k * 192 + 128 + j] : 0.f;
    }
    #pragma unroll
    for (int i = 0; i < 22; ++i)
      asm volatile("" : "+v"(wz[i]), "+v"(wr[i]), "+v"(wh[i]));

    // bias seeds: only wave 0 carries the bias (fixed-order partial sum).
    float seedz = (w == 0) ? bg[192 + j]       : 0.f;
    float seedr = (w == 0) ? bg[192 + 64 + j]  : 0.f;
    float seedh = (w == 0) ? bg[192 + 128 + j] : 0.f;
    float hreg = 0.f;

    const uint4* xp = (const uint4*)(xg + (size_t)(b * 64 + j) * L_ * 4);
    uint4 cur_ = xp[0];
    uint4 nxt_ = xp[1];

#define STEP(WZR, WH_, P) { \
    float hk[22]; \
    _Pragma("unroll") \
    for (int i = 0; i < 22; ++i) \
      hk[i] = __int_as_float(__builtin_amdgcn_readlane(__float_as_int(hreg), (kb + i) & 63)); \
    __builtin_amdgcn_sched_barrier(0); \
    float az[4] = {seedz, 0.f, 0.f, 0.f}; \
    float ar[4] = {seedr, 0.f, 0.f, 0.f}; \
    float ah[4] = {seedh, 0.f, 0.f, 0.f}; \
    _Pragma("unroll") \
    for (int i = 0; i < 22; ++i) { \
      az[i & 3] = fmaf(hk[i], wz[i], az[i & 3]); \
      ar[i & 3] = fmaf(hk[i], wr[i], ar[i & 3]); \
      ah[i & 3] = fmaf(hk[i], wh[i], ah[i & 3]); \
    } \
    float4 pv; \
    pv.x = (az[0] + az[1]) + (az[2] + az[3]); \
    pv.y = (ar[0] + ar[1]) + (ar[2] + ar[3]); \
    pv.z = (ah[0] + ah[1]) + (ah[2] + ah[3]); \
    pv.w = 0.f; \
    *((float4*)&xch[(P) * 768 + (w * 64 + j) * 4]) = pv; \
    BARRIER(); \
    float4 q0 = *((const float4*)&xch[(P) * 768 + (0 * 64 + j) * 4]); \
    float4 q1 = *((const float4*)&xch[(P) * 768 + (1 * 64 + j) * 4]); \
    float4 q2 = *((const float4*)&xch[(P) * 768 + (2 * 64 + j) * 4]); \
    float sz = (q0.x + q1.x) + q2.x; \
    float sr = (q0.y + q1.y) + q2.y; \
    float sh = (q0.z + q1.z) + q2.z; \
    float xvz = bf2f((unsigned short)((WZR) & 0xffffu)); \
    float xvr = bf2f((unsigned short)((WZR) >> 16)); \
    float xvh = bf2f((unsigned short)((WH_) & 0xffffu)); \
    float zg = 1.f / (1.f + __expf(-(xvz + sz))); \
    float rg = 1.f / (1.f + __expf(-(xvr + sr))); \
    float e2 = __expf(-2.f * (xvh + rg * sh)); \
    float hh = fmaf(2.f, __frcp_rn(1.f + e2), -1.f); \
    hreg = zg * hreg + (1.f - zg) * hh; \
  }

    #pragma nounroll
    for (int p = 0; p < L_ / 2; ++p) {
      int pn = (p < L_ / 2 - 2) ? p + 2 : (L_ / 2 - 1);
      uint4 nn = xp[pn];
      STEP(cur_.x, cur_.y, 0)
      STEP(cur_.z, cur_.w, 1)
      cur_ = nxt_; nxt_ = nn;
    }
#undef STEP
    if (w == 0) h_t[b * 64 + j] = hreg;
    return;
  }

  // ================= fused conv1+conv2 (halo recompute) =================
  unsigned short* At    = pool;           // 152 x 136 shorts = 41344 B
  unsigned short* l1buf = pool + 20672;   // 144 x 72  shorts = 20736 B
  unsigned short* Bw    = pool + 31040;   //  64 x 136 shorts = 17408 B
  int wv = tid >> 6, lane = tid & 63;
  int m = lane & 15, q = lane >> 4;

  for (int job = bid - 64; job < 1024; job += 192) {
    int b = job >> 4;
    int l0 = (job & 15) << 7;
    __syncthreads();                      // prev job fully consumed
    for (int i = tid; i < 152 * 16; i += 192) {
      int row = i >> 4, c8 = i & 15;
      int p = l0 - 3 + row;
      p = p < 0 ? 0 : (p > 2055 ? 2055 : p);
      *((uint4*)&At[row * 136 + c8 * 8]) = ((const uint4*)tokpad)[(b * LP + p) * 16 + c8];
    }
    // ---- conv1: l1 rows [l0-3, l0+140] (9 M-tiles of 16), K=128 ----
    f32x4 acc[3][4];
    #pragma unroll
    for (int mt = 0; mt < 3; ++mt)
      #pragma unroll
      for (int nt = 0; nt < 4; ++nt) acc[mt][nt] = (f32x4){0.f,0.f,0.f,0.f};
    for (int w8 = 0; w8 < 8; ++w8) {
      __syncthreads();
      for (int i = tid; i < 64 * 16; i += 192) {
        int row = i >> 4, c8 = i & 15;
        *((uint4*)&Bw[row * 136 + c8 * 8]) = ((const uint4*)c1wT)[(w8 * 64 + row) * 16 + c8];
      }
      __syncthreads();
      #pragma unroll
      for (int ks = 0; ks < 4; ++ks) {
        int kof = ks * 32 + q * 8;
        short8 a[3], bb[4];
        #pragma unroll
        for (int mt = 0; mt < 3; ++mt) {
          int tl = wv + 3 * mt;
          a[mt] = *(const short8*)&At[(tl * 16 + m + w8) * 136 + kof];
        }
        #pragma unroll
        for (int nt = 0; nt < 4; ++nt)
          bb[nt] = *(const short8*)&Bw[(nt * 16 + m) * 136 + kof];
        #pragma unroll
        for (int mt = 0; mt < 3; ++mt)
          #pragma unroll
          for (int nt = 0; nt < 4; ++nt)
            acc[mt][nt] = __builtin_amdgcn_mfma_f32_16x16x32_bf16(a[mt], bb[nt], acc[mt][nt], 0, 0, 0);
      }
    }
    #pragma unroll
    for (int mt = 0; mt < 3; ++mt) {
      int tl = wv + 3 * mt;
      #pragma unroll
      for (int nt = 0; nt < 4; ++nt) {
        int c = nt * 16 + m;
        float bs = c1b[c];
        #pragma unroll
        for (int r = 0; r < 4; ++r) {
          float v = fmaxf(acc[mt][nt][r] + bs, 0.f);
          l1buf[(tl * 16 + q * 4 + r) * 72 + c] = f2bf(v);
        }
      }
    }
    __syncthreads();
    for (int i2 = tid; i2 < 135 * 8; i2 += 192) {
      int i = i2 >> 3, c8 = i2 & 7;
      int jrow = l0 - 3 + i;
      if (jrow < 0 || jrow > 2047) {
        uint4 z4 = {0u,0u,0u,0u};
        *((uint4*)&l1buf[i * 72 + c8 * 8]) = z4;
      }
    }
    // ---- conv2: out rows [l0, l0+127] (8 M-tiles), K=64 ----
    f32x4 acc2[3][4];
    #pragma unroll
    for (int mt = 0; mt < 3; ++mt)
      #pragma unroll
      for (int nt = 0; nt < 4; ++nt) acc2[mt][nt] = (f32x4){0.f,0.f,0.f,0.f};
    for (int w8 = 0; w8 < 8; ++w8) {
      __syncthreads();
      for (int i = tid; i < 64 * 8; i += 192) {
        int row = i >> 3, c8 = i & 7;
        *((uint4*)&Bw[row * 72 + c8 * 8]) = ((const uint4*)c2wT)[(w8 * 64 + row) * 8 + c8];
      }
      __syncthreads();
      #pragma unroll
      for (int ks = 0; ks < 2; ++ks) {
        int kof = ks * 32 + q * 8;
        short8 a[3], bb[4];
        #pragma unroll
        for (int mt = 0; mt < 3; ++mt) {
          int tl = wv + 3 * mt;
          if (tl < 8)
            a[mt] = *(const short8*)&l1buf[(tl * 16 + m + w8) * 72 + kof];
        }
        #pragma unroll
        for (int nt = 0; nt < 4; ++nt)
          bb[nt] = *(const short8*)&Bw[(nt * 16 + m) * 72 + kof];
        #pragma unroll
        for (int mt = 0; mt < 3; ++mt) {
          int tl = wv + 3 * mt;
          if (tl < 8)
            #pragma unroll
            for (int nt = 0; nt < 4; ++nt)
              acc2[mt][nt] = __builtin_amdgcn_mfma_f32_16x16x32_bf16(a[mt], bb[nt], acc2[mt][nt], 0, 0, 0);
        }
      }
    }
    #pragma unroll
    for (int mt = 0; mt < 3; ++mt) {
      int tl = wv + 3 * mt;
      if (tl < 8) {
        #pragma unroll
        for (int nt = 0; nt < 4; ++nt) {
          int c = nt * 16 + m;
          float bs = c2b[c];
          #pragma unroll
          for (int r = 0; r < 4; ++r)
            c2o[(size_t)(b * L_ + l0 + tl * 16 + q * 4 + r) * 64 + c] = f2bf(acc2[mt][nt][r] + bs);
        }
      }
    }
  }
}

// ---------------------------------------------------------------------------
// K3: a_logits, one block per (batch, 64-l tile) — verbatim R19 k_alpha.
// ---------------------------------------------------------------------------
__global__ __launch_bounds__(256) void k_alpha(
    const unsigned short* __restrict__ c2o, const float* __restrict__ h_t,
    const float* __restrict__ c3w, const float* __restrict__ c3b,
    float* __restrict__ a_out)
{
  __shared__ float Lf[71 * 65];
  __shared__ float red[256];
  __shared__ float ht[64];
  __shared__ float c3[512];
  int b = blockIdx.x >> 5;
  int tile = blockIdx.x & 31;
  int tid = threadIdx.x, lane = tid & 63, wave = tid >> 6;
  if (tid < 64) ht[tid] = h_t[b * 64 + tid];
  for (int i = tid; i < 512; i += 256) c3[i] = c3w[i];
  float c3bias = c3b[0];
  __syncthreads();
  int lt = tile << 6;
  for (int i0 = wave; i0 < 71; i0 += 4) {
    int l = lt - 3 + i0;
    float v = 0.f;
    if (l >= 0 && l < L_) v = bf2f(c2o[((size_t)b * L_ + l) * 64 + lane]) * ht[lane];
    float ss = v * v;
    #pragma unroll
    for (int msk = 1; msk < 64; msk <<= 1) ss += __shfl_xor(ss, msk);
    Lf[i0 * 65 + lane] = v * rsqrtf(ss + 1e-12f);
  }
  __syncthreads();
  {
    int u = lane, part = wave;
    float p = 0.f;
    #pragma unroll
    for (int w = 0; w < 8; ++w)
      #pragma unroll
      for (int cc = 0; cc < 16; ++cc) {
        int c = part * 16 + cc;
        p += Lf[(u + w) * 65 + c] * c3[w * 64 + c];
      }
    red[tid] = p;
  }
  __syncthreads();
  if (tid < 64)
    a_out[b * L_ + lt + tid] = red[tid] + red[64 + tid] + red[128 + tid] + red[192 + tid] + c3bias;
}

// ---------------------------------------------------------------------------
// K4 (R20): alpha softmax over 2048, per batch, in-place (pass 2 verbatim).
// ---------------------------------------------------------------------------
__global__ __launch_bounds__(256) void k_soft1(float* __restrict__ a)
{
  __shared__ float a_lds[2048];
  __shared__ float red[256];
  int b = blockIdx.x, tid = threadIdx.x, lane = tid & 63, wave = tid >> 6;
  for (int i = tid; i < 2048; i += 256) a_lds[i] = a[b * L_ + i];
  __syncthreads();
  float mx = -1e30f;
  for (int i = tid; i < 2048; i += 256) mx = fmaxf(mx, a_lds[i]);
  #pragma unroll
  for (int msk = 1; msk < 64; msk <<= 1) mx = fmaxf(mx, __shfl_xor(mx, msk));
  if (lane == 0) red[wave] = mx;
  __syncthreads();
  mx = fmaxf(fmaxf(red[0], red[1]), fmaxf(red[2], red[3]));
  float sm = 0.f;
  for (int i = tid; i < 2048; i += 256) sm += __expf(a_lds[i] - mx);
  #pragma unroll
  for (int msk = 1; msk < 64; msk <<= 1) sm += __shfl_xor(sm, msk);
  __syncthreads();
  if (lane == 0) red[wave] = sm;
  __syncthreads();
  sm = red[0] + red[1] + red[2] + red[3];
  float inv = 1.f / sm;
  for (int i = tid; i < 2048; i += 256) a[b * L_ + i] = __expf(a_lds[i] - mx) * inv;
}

// ---------------------------------------------------------------------------
// K5 (R20): partial n_hat per (b, 256-l chunk). Inner per-g stride-4 sum as
// in the old pass 3; chunk-level f32 reassociation (established invisible).
// ---------------------------------------------------------------------------
__global__ __launch_bounds__(256) void k_nhat(
    const unsigned short* __restrict__ tokpad, const float* __restrict__ alpha,
    float* __restrict__ npart)
{
  __shared__ float nred[512];
  int b = blockIdx.x >> 3, c = blockIdx.x & 7;
  int tid = threadIdx.x;
  int d2 = tid & 63, g = tid >> 6;
  int l0 = c << 8;
  float ax = 0.f, ay = 0.f;
  for (int i = 0; i < 64; ++i) {
    int l = l0 + g + 4 * i;
    unsigned int uu = *(const unsigned int*)&tokpad[((size_t)b * LP + PAD + l) * 128 + d2 * 2];
    float al = alpha[b * L_ + l];
    ax += al * bf2f((unsigned short)(uu & 0xffffu));
    ay += al * bf2f((unsigned short)(uu >> 16));
  }
  nred[g * 128 + d2 * 2] = ax;
  nred[g * 128 + d2 * 2 + 1] = ay;
  __syncthreads();
  if (tid < 128)
    npart[((b << 3) + c) * 128 + tid] = nred[tid] + nred[128 + tid] + nred[256 + tid] + nred[384 + tid];
}

// ---------------------------------------------------------------------------
// K6 (R20): combine npart -> nhat (LDS), then 256 logits per block
// (pass-4 dot verbatim) -> l_all.
// ---------------------------------------------------------------------------
__global__ __launch_bounds__(256) void k_logits(
    const unsigned short* __restrict__ tokpad, const float* __restrict__ npart,
    const float* __restrict__ biasg, float* __restrict__ l_all)
{
  __shared__ float nhat[128];
  int b = blockIdx.x >> 3, c = blockIdx.x & 7;
  int tid = threadIdx.x;
  if (tid < 128) {
    const float* p = npart + (b << 3) * 128 + tid;
    nhat[tid] = ((p[0] + p[128]) + (p[256] + p[384]))
              + ((p[512] + p[640]) + (p[768] + p[896]));
  }
  __syncthreads();
  int l = (c << 8) + tid;
  const uint4* rowp = (const uint4*)&tokpad[((size_t)b * LP + PAD + l) * 128];
  float s = 0.f;
  #pragma unroll
  for (int jj = 0; jj < 16; ++jj) {
    uint4 uu = rowp[jj];
    s += bf2f((unsigned short)(uu.x & 0xffffu)) * nhat[jj*8+0]
       + bf2f((unsigned short)(uu.x >> 16))     * nhat[jj*8+1]
       + bf2f((unsigned short)(uu.y & 0xffffu)) * nhat[jj*8+2]
       + bf2f((unsigned short)(uu.y >> 16))     * nhat[jj*8+3]
       + bf2f((unsigned short)(uu.z & 0xffffu)) * nhat[jj*8+4]
       + bf2f((unsigned short)(uu.z >> 16))     * nhat[jj*8+5]
       + bf2f((unsigned short)(uu.w & 0xffffu)) * nhat[jj*8+6]
       + bf2f((unsigned short)(uu.w >> 16))     * nhat[jj*8+7];
  }
  l_all[b * L_ + l] = s + biasg[b * L_ + l];
}

// ---------------------------------------------------------------------------
// K7 (R20): final softmax per batch (pass 5 verbatim) -> out.
// ---------------------------------------------------------------------------
__global__ __launch_bounds__(256) void k_soft2(
    const float* __restrict__ l_all, float* __restrict__ out)
{
  __shared__ float l_lds[2048];
  __shared__ float red[256];
  int b = blockIdx.x, tid = threadIdx.x, lane = tid & 63, wave = tid >> 6;
  for (int i = tid; i < 2048; i += 256) l_lds[i] = l_all[b * L_ + i];
  __syncthreads();
  float mx = -1e30f;
  for (int i = tid; i < 2048; i += 256) mx = fmaxf(mx, l_lds[i]);
  #pragma unroll
  for (int msk = 1; msk < 64; msk <<= 1) mx = fmaxf(mx, __shfl_xor(mx, msk));
  __syncthreads();
  if (lane == 0) red[wave] = mx;
  __syncthreads();
  mx = fmaxf(fmaxf(red[0], red[1]), fmaxf(red[2], red[3]));
  float sm = 0.f;
  for (int i = tid; i < 2048; i += 256) sm += __expf(l_lds[i] - mx);
  #pragma unroll
  for (int msk = 1; msk < 64; msk <<= 1) sm += __shfl_xor(sm, msk);
  __syncthreads();
  if (lane == 0) red[wave] = sm;
  __syncthreads();
  sm = red[0] + red[1] + red[2] + red[3];
  float inv = 1.f / sm;
  for (int i = tid; i < 2048; i += 256) out[b * L_ + i] = __expf(l_lds[i] - mx) * inv;
}

// ---------------------------------------------------------------------------
extern "C" void kernel_launch(void* const* d_in, const int* in_sizes, int n_in,
                              void* d_out, int out_size, void* d_ws, size_t ws_size,
                              hipStream_t stream) {
  const int*   code = (const int*)d_in[0];
  const float* E    = (const float*)d_in[1];
  const float* bt   = (const float*)d_in[2];
  const float* Wx   = (const float*)d_in[3];
  const float* Wh   = (const float*)d_in[4];
  const float* bg   = (const float*)d_in[5];
  const float* c1w  = (const float*)d_in[6];
  const float* c1b  = (const float*)d_in[7];
  const float* c2w  = (const float*)d_in[8];
  const float* c2b  = (const float*)d_in[9];
  const float* c3w  = (const float*)d_in[10];
  const float* c3b  = (const float*)d_in[11];
  char* ws = (char*)d_ws;
  unsigned short* tokpad = (unsigned short*)(ws);               // 33,685,504 B
  unsigned short* xg     = (unsigned short*)(ws + 33685504);    // 67,108,864 B
  unsigned short* c2o    = (unsigned short*)(ws + 100794368);   // 16,777,216 B
  unsigned short* WxT    = (unsigned short*)(ws + 117571584);   //     49,152 B
  unsigned short* c1wT   = (unsigned short*)(ws + 117620736);   //    131,072 B
  unsigned short* c2wT   = (unsigned short*)(ws + 117751808);   //     65,536 B
  float*          htp    = (float*)(ws + 117817344);            //     16,384 B
  float*          biasg  = (float*)(ws + 117833728);            //    524,288 B
  // tail buffers reuse xg space (dead after k_fused):
  float*          alog   = (float*)(ws + 33685504);             //    524,288 B
  float*          npart  = (float*)(ws + 33685504 + 1048576);   //    262,144 B
  float*          l_all  = (float*)(ws + 33685504 + 2097152);   //    524,288 B
  // total ws use: 118,358,016 B

  k_prep  <<<9216, 256, 0, stream>>>(code, E, bt, Wx, c1w, c2w, tokpad, WxT, c1wT, c2wT, biasg);
  k_xproj <<<1024, 256, 0, stream>>>(tokpad, WxT, bg, xg);
  k_fused <<<256, 192, 0, stream>>>(xg, Wh, bg, htp, tokpad, c1wT, c1b, c2wT, c2b, c2o);
  k_alpha <<<2048, 256, 0, stream>>>(c2o, htp, c3w, c3b, alog);
  k_soft1 <<<64, 256, 0, stream>>>(alog);
  k_nhat  <<<512, 256, 0, stream>>>(tokpad, alog, npart);
  k_logits<<<512, 256, 0, stream>>>(tokpad, npart, biasg, l_all);
  k_soft2 <<<64, 256, 0, stream>>>(l_all, (float*)d_out);
}